// Round 7
// baseline (420.757 us; speedup 1.0000x reference)
//
#include <hip/hip_runtime.h>
#include <math.h>

#define EPS 1e-5f

typedef _Float16 half8 __attribute__((ext_vector_type(8)));
typedef float f32x4 __attribute__((ext_vector_type(4)));

// bq in [0,96): b = bq/12, t = bq%12; x1seq row = b*12 + min(t+1, 11)
__device__ __forceinline__ int src_row(int bq) {
    int b = bq / 12, t = bq - b * 12;
    int t2 = (t + 1 < 12) ? (t + 1) : 11;
    return b * 12 + t2;
}

// ---------------- erase0: y0vec[bq][o] = BN(W_e @ mean_n(x) + b_e) ----------------
__global__ __launch_bounds__(256) void erase0_kernel(
    const float* __restrict__ x, const float* __restrict__ w_e,
    const float* __restrict__ b_e, const float* __restrict__ g_e,
    const float* __restrict__ be_e, const float* __restrict__ m_e,
    const float* __restrict__ v_e, float* __restrict__ y0vec)
{
    __shared__ float part[256];
    __shared__ float res[64];
    int bq = blockIdx.x, tid = threadIdx.x;
    int c = tid >> 2, p = tid & 3;
    const float* xb = x + (size_t)bq * 32768 + c * 512 + p * 128;
    float acc = 0.f;
    for (int ii = 0; ii < 128; ii += 4) {
        float4 v = *(const float4*)(xb + ii);
        acc += v.x + v.y + v.z + v.w;
    }
    part[tid] = acc;
    __syncthreads();
    if (p == 0) res[c] = (part[tid] + part[tid+1] + part[tid+2] + part[tid+3]) * (1.f/512.f);
    __syncthreads();
    if (tid < 64) {
        float a = b_e[tid];
        for (int cc = 0; cc < 64; ++cc) a += w_e[tid*64+cc] * res[cc];
        float s = g_e[tid] / sqrtf(v_e[tid] + EPS);
        y0vec[bq*64 + tid] = (a - m_e[tid]) * s + be_e[tid];
    }
}

// ---------------- prep dual + W' split ----------------
// grid = 1536. blockIdx = q*96 + bq, q=0..15: ct=q&7, half=q>>3.
__global__ __launch_bounds__(256) void prep_kernel(
    const float* __restrict__ X, const float* __restrict__ vec,
    _Float16* __restrict__ H0, _Float16* __restrict__ L0, float* __restrict__ xn0,
    _Float16* __restrict__ H1, _Float16* __restrict__ L1, float* __restrict__ xn1,
    const float* __restrict__ w0, const float* __restrict__ w1,
    _Float16* __restrict__ wh0, _Float16* __restrict__ wl0,
    _Float16* __restrict__ wh1, _Float16* __restrict__ wl1)
{
    __shared__ float lds[64 * 65];     // [c][col] pad
    __shared__ float xnp[4 * 64];
    int raw = blockIdx.x;
    int bq = raw % 96;
    int q = raw / 96;
    int ct = q & 7, half = q >> 3;
    int row = half ? src_row(bq) : bq;
    _Float16* H = half ? H1 : H0;
    _Float16* L = half ? L1 : L0;
    float* xn = half ? xn1 : xn0;
    const float* vp = half ? nullptr : vec;
    const float* Xb = X + (size_t)row * 32768 + ct * 64;
    int tid = threadIdx.x;
    for (int p = 0; p < 16; ++p) {
        int t = p * 256 + tid;
        int c = t >> 6, col = t & 63;
        float v = Xb[c * 512 + col];
        if (vp) v += vp[bq * 64 + c];
        lds[c * 65 + col] = v;
    }
    __syncthreads();
    int col = tid & 63, g = tid >> 6;       // g: group of 16 channels
    half8 hv[2], lv[2];
    float s = 0.f;
    #pragma unroll
    for (int k = 0; k < 16; ++k) {
        int c = g * 16 + k;
        float v = lds[c * 65 + col];
        _Float16 h = (_Float16)v;
        _Float16 lo = (_Float16)(v - (float)h);
        hv[k >> 3][k & 7] = h;
        lv[k >> 3][k & 7] = lo;
        s += v * v;
    }
    size_t obase = ((size_t)bq * 512 + ct * 64 + col) * 64 + g * 16;
    *(half8*)(H + obase) = hv[0];
    *(half8*)(H + obase + 8) = hv[1];
    *(half8*)(L + obase) = lv[0];
    *(half8*)(L + obase + 8) = lv[1];
    xnp[g * 64 + col] = s;
    __syncthreads();
    if (tid < 64)
        xn[bq * 512 + ct * 64 + tid] =
            xnp[tid] + xnp[64 + tid] + xnp[128 + tid] + xnp[192 + tid];
    // W' split for branch raw (raw<2): Wp[o][c], o<64: W1, o>=64: W2-W1
    if (raw < 2) {
        const float* W = raw ? w1 : w0;
        _Float16* WH = raw ? wh1 : wh0;
        _Float16* WL = raw ? wl1 : wl0;
        for (int t = tid; t < 8192; t += 256) {
            int o = t >> 6, c = t & 63;
            float v = (o < 64) ? W[o * 128 + c]
                               : (W[(o - 64) * 128 + 64 + c] - W[(o - 64) * 128 + c]);
            _Float16 h = (_Float16)v;
            WH[t] = h;
            WL[t] = (_Float16)(v - (float)h);
        }
    }
}

// ---------------- kNN: transposed MFMA + Batcher sort-16 selection (dual-capable) ----------------
// grid = 1536 (dual) or 768 (single). blockIdx = q*96+bq, itile=q&7, half=q>>3.
// __launch_bounds__(256,4): VGPR budget 128 -> no scratch spills in the sort network.
__global__ __launch_bounds__(256, 4) void knn_kernel(
    const _Float16* __restrict__ H0, const _Float16* __restrict__ L0,
    const float* __restrict__ xn0, int* __restrict__ idx0, int k0,
    const _Float16* __restrict__ H1, const _Float16* __restrict__ L1,
    const float* __restrict__ xn1, int* __restrict__ idx1, int k1)
{
    __shared__ float          ldsMV[4][64 * 17];   // per wave: 64 lists x 16 vals, pad 17
    __shared__ unsigned short ldsMJ[4][64 * 17];
    int raw = blockIdx.x;
    int bq = raw % 96;
    int q = raw / 96;
    int itile = q & 7, half = q >> 3;
    const _Float16* H = half ? H1 : H0;
    const _Float16* L = half ? L1 : L0;
    const float* xn = half ? xn1 : xn0;
    int* idx_out = half ? idx1 : idx0;
    int K = half ? k1 : k0;
    int tid = threadIdx.x, w = tid >> 6, l = tid & 63;
    int lane16 = l & 15, quad = l >> 4;
    const size_t base = (size_t)bq * 512 * 64;
    int irow = itile * 64 + w * 16 + lane16;
    const _Float16* Hi = H + base + (size_t)irow * 64 + quad * 8;
    const _Float16* Li = L + base + (size_t)irow * 64 + quad * 8;
    half8 Bh0 = *(const half8*)(Hi);
    half8 Bh1 = *(const half8*)(Hi + 32);
    half8 Bl0 = *(const half8*)(Li);
    half8 Bl1 = *(const half8*)(Li + 32);

    float kv[16]; int kj[16];              // running top-16, ascending (kv[15]=best)
    #pragma unroll
    for (int qq = 0; qq < 16; ++qq) { kv[qq] = -3.4e38f; kj[qq] = 0; }

    auto cas_asc = [](float& va, int& ja, float& vb, int& jb2) {
        bool sw = va > vb;
        float tv = va; int tj = ja;
        va = sw ? vb : va; ja = sw ? jb2 : ja;
        vb = sw ? tv : vb; jb2 = sw ? tj : jb2;
    };

    const float* xnb = xn + bq * 512;
    for (int jt = 0; jt < 8; ++jt) {
        float d[16]; int jd[16];
        // issue all 16 j-loads for this jt up front (one waitcnt), then MFMA
        half8 Ah0[4], Ah1[4], Al0[4], Al1[4];
        #pragma unroll
        for (int g = 0; g < 4; ++g) {
            int jrow = jt * 64 + g * 16 + lane16;
            const _Float16* Hj = H + base + (size_t)jrow * 64 + quad * 8;
            const _Float16* Lj = L + base + (size_t)jrow * 64 + quad * 8;
            Ah0[g] = *(const half8*)(Hj);
            Ah1[g] = *(const half8*)(Hj + 32);
            Al0[g] = *(const half8*)(Lj);
            Al1[g] = *(const half8*)(Lj + 32);
        }
        #pragma unroll
        for (int g = 0; g < 4; ++g) {
            f32x4 acc = {0.f, 0.f, 0.f, 0.f};
            acc = __builtin_amdgcn_mfma_f32_16x16x32_f16(Ah0[g], Bh0, acc, 0, 0, 0);
            acc = __builtin_amdgcn_mfma_f32_16x16x32_f16(Ah1[g], Bh1, acc, 0, 0, 0);
            acc = __builtin_amdgcn_mfma_f32_16x16x32_f16(Al0[g], Bh0, acc, 0, 0, 0);
            acc = __builtin_amdgcn_mfma_f32_16x16x32_f16(Al1[g], Bh1, acc, 0, 0, 0);
            acc = __builtin_amdgcn_mfma_f32_16x16x32_f16(Ah0[g], Bl0, acc, 0, 0, 0);
            acc = __builtin_amdgcn_mfma_f32_16x16x32_f16(Ah1[g], Bl1, acc, 0, 0, 0);
            // (L*L term dropped: ~3e-7, below fp32 accumulation noise)
            int jb = jt * 64 + g * 16 + quad * 4;   // lane holds j = jb..jb+3, col = irow
            float4 xn4 = *(const float4*)&xnb[jb];
            d[g * 4 + 0] = 2.f * acc[0] - xn4.x; jd[g * 4 + 0] = jb + 0;
            d[g * 4 + 1] = 2.f * acc[1] - xn4.y; jd[g * 4 + 1] = jb + 1;
            d[g * 4 + 2] = 2.f * acc[2] - xn4.z; jd[g * 4 + 2] = jb + 2;
            d[g * 4 + 3] = 2.f * acc[3] - xn4.w; jd[g * 4 + 3] = jb + 3;
        }
        // Batcher odd-even mergesort-16 ascending: 63 CAS, fully static after unroll
        #pragma unroll
        for (int p = 1; p < 16; p <<= 1) {
            #pragma unroll
            for (int k = p; k >= 1; k >>= 1) {
                #pragma unroll
                for (int j = k & (p - 1); j + k < 16; j += 2 * k) {
                    #pragma unroll
                    for (int i = 0; i < k; ++i) {
                        if ((i + j + k < 16) &&
                            ((i + j) / (2 * p) == (i + j + k) / (2 * p)))
                            cas_asc(d[i + j], jd[i + j], d[i + j + k], jd[i + j + k]);
                    }
                }
            }
        }
        // exact top-16 of (kv ∪ d): max-trick (result bitonic), then bitonic clean
        #pragma unroll
        for (int i = 0; i < 16; ++i) {
            bool take = kv[i] >= d[15 - i];
            kv[i] = take ? kv[i] : d[15 - i];
            kj[i] = take ? kj[i] : jd[15 - i];
        }
        #pragma unroll
        for (int jj = 8; jj > 0; jj >>= 1) {
            #pragma unroll
            for (int i = 0; i < 16; ++i) {
                int lo = i ^ jj;
                if (lo > i) cas_asc(kv[i], kj[i], kv[lo], kj[lo]);
            }
        }
    }
    // dump sorted-16 per quad (pad-17 stride), merge 4 lists per row
    #pragma unroll
    for (int qq = 0; qq < 16; ++qq) {
        ldsMV[w][(lane16 * 4 + quad) * 17 + qq] = kv[qq];
        ldsMJ[w][(lane16 * 4 + quad) * 17 + qq] = (unsigned short)kj[qq];
    }
    __syncthreads();
    if (quad == 0) {
        const float* MV = &ldsMV[w][lane16 * 68];
        const unsigned short* MJ = &ldsMJ[w][lane16 * 68];
        int p0 = 15, p1 = 15, p2 = 15, p3 = 15;
        int* op = idx_out + ((size_t)bq * 512 + irow) * 16;
        for (int t = 0; t < K; ++t) {
            float bv = -3.4e38f; int bj = 0x7fffffff; int bc = -1;
            { float v = MV[p0]; int j = MJ[p0];
              if (v > bv || (v == bv && j < bj)) { bv = v; bj = j; bc = 0; } }
            { float v = MV[17 + p1]; int j = MJ[17 + p1];
              if (v > bv || (v == bv && j < bj)) { bv = v; bj = j; bc = 1; } }
            { float v = MV[34 + p2]; int j = MJ[34 + p2];
              if (v > bv || (v == bv && j < bj)) { bv = v; bj = j; bc = 2; } }
            { float v = MV[51 + p3]; int j = MJ[51 + p3];
              if (v > bv || (v == bv && j < bj)) { bv = v; bj = j; bc = 3; } }
            if (bc == 0) --p0; else if (bc == 1) --p1; else if (bc == 2) --p2; else --p3;
            op[t] = bj;
        }
    }
}

// ---------------- MFMA gemm: AB[bq] = W' (128x64) @ X (64x512), split-fp16 ----------------
// blockIdx = itile*96 + bq (XCD swizzle). No LDS, no barriers. (256,4): no spills.
__global__ __launch_bounds__(256, 4) void gemm_mfma_kernel(
    const _Float16* __restrict__ H, const _Float16* __restrict__ L,
    const _Float16* __restrict__ WH, const _Float16* __restrict__ WL,
    float* __restrict__ AB)
{
    int raw = blockIdx.x;
    int bq = raw % 96;
    int itile = raw / 96;
    int tid = threadIdx.x, w = tid >> 6, l = tid & 63;
    int lane16 = l & 15, quad = l >> 4;
    const size_t xbase = (size_t)bq * 32768;
    half8 Bh0[4], Bh1[4], Bl0[4], Bl1[4];
    #pragma unroll
    for (int it = 0; it < 4; ++it) {
        size_t off = xbase + (size_t)(itile * 64 + it * 16 + lane16) * 64 + quad * 8;
        Bh0[it] = *(const half8*)(H + off);
        Bh1[it] = *(const half8*)(H + off + 32);
        Bl0[it] = *(const half8*)(L + off);
        Bl1[it] = *(const half8*)(L + off + 32);
    }
    float* ABb = AB + (size_t)bq * 65536 + itile * 64;
    #pragma unroll
    for (int oo = 0; oo < 2; ++oo) {
        int ot = w * 2 + oo;
        size_t woff = (size_t)(ot * 16 + lane16) * 64 + quad * 8;
        half8 Ah0 = *(const half8*)(WH + woff);
        half8 Ah1 = *(const half8*)(WH + woff + 32);
        half8 Al0 = *(const half8*)(WL + woff);
        half8 Al1 = *(const half8*)(WL + woff + 32);
        #pragma unroll
        for (int it = 0; it < 4; ++it) {
            f32x4 acc = {0.f, 0.f, 0.f, 0.f};
            acc = __builtin_amdgcn_mfma_f32_16x16x32_f16(Ah0, Bh0[it], acc, 0, 0, 0);
            acc = __builtin_amdgcn_mfma_f32_16x16x32_f16(Ah1, Bh1[it], acc, 0, 0, 0);
            acc = __builtin_amdgcn_mfma_f32_16x16x32_f16(Ah0, Bl0[it], acc, 0, 0, 0);
            acc = __builtin_amdgcn_mfma_f32_16x16x32_f16(Ah1, Bl1[it], acc, 0, 0, 0);
            acc = __builtin_amdgcn_mfma_f32_16x16x32_f16(Al0, Bh0[it], acc, 0, 0, 0);
            acc = __builtin_amdgcn_mfma_f32_16x16x32_f16(Al1, Bh1[it], acc, 0, 0, 0);
            #pragma unroll
            for (int r = 0; r < 4; ++r)
                ABb[(size_t)(ot * 16 + quad * 4 + r) * 512 + it * 16 + lane16] = acc[r];
        }
    }
}

// ---------------- branch epilogue: grid (96,4), 16 o's per block ----------------
template<int ACC>
__global__ __launch_bounds__(256) void branch_reduce_kernel(
    const float* __restrict__ AB, const int* __restrict__ idx,
    const float* __restrict__ g, const float* __restrict__ bb,
    const float* __restrict__ mm, const float* __restrict__ vv,
    float* __restrict__ out_p, float* __restrict__ vec_out)
{
    __shared__ float ldsA[16 * 512];       // 32 KB: A-chunk [o][i]
    __shared__ int   ldsIdx[512 * 10];     // 20 KB
    int bq = blockIdx.x, ob = blockIdx.y * 16;
    int tid = threadIdx.x;
    int w = tid >> 6, ln = tid & 63;
    for (int p = 0; p < 20; ++p) {
        int t = p * 256 + tid;
        int i = t / 10, q = t - i * 10;
        ldsIdx[t] = idx[((size_t)bq * 512 + i) * 16 + q];
    }
    const float* ABb = AB + (size_t)bq * 65536;
    for (int p = 0; p < 8; ++p) {
        int t = p * 256 + tid;             // float4 index into 16*512
        int o = t >> 7, i4 = t & 127;
        *(float4*)&ldsA[o * 512 + i4 * 4] = *(const float4*)&ABb[(size_t)(ob + o) * 512 + i4 * 4];
    }
    float ssr[4], str[4];
    #pragma unroll
    for (int oo = 0; oo < 4; ++oo) {
        int o = ob + w * 4 + oo;
        float sc = g[o] / sqrtf(vv[o] + EPS);
        ssr[oo] = sc;
        str[oo] = bb[o] - mm[o] * sc;
    }
    __syncthreads();
    float omax[4], osum[4];
    #pragma unroll
    for (int oo = 0; oo < 4; ++oo) { omax[oo] = -3.4e38f; osum[oo] = 0.f; }
    const float* Aw = ldsA + (w * 4) * 512;
    for (int s = 0; s < 8; ++s) {
        int i = ln + 64 * s;
        int idr[10];
        const int* ip = &ldsIdx[i * 10];
        #pragma unroll
        for (int q = 0; q < 10; ++q) idr[q] = ip[q];
        #pragma unroll
        for (int oo = 0; oo < 4; ++oo) {
            const float* Ao = Aw + oo * 512;
            float mx = Ao[idr[0]];
            #pragma unroll
            for (int q = 1; q < 10; ++q) mx = fmaxf(mx, Ao[idr[q]]);
            float Bv = ABb[(size_t)(64 + ob + w * 4 + oo) * 512 + i];
            float val = (mx + Bv) * ssr[oo] + str[oo];
            float y = val > 0.f ? val : 0.2f * val;
            omax[oo] = fmaxf(omax[oo], y);
            osum[oo] += y;
        }
    }
    #pragma unroll
    for (int oo = 0; oo < 4; ++oo) {
        float M = omax[oo], S = osum[oo];
        #pragma unroll
        for (int off = 32; off >= 1; off >>= 1) {
            M = fmaxf(M, __shfl_down(M, off));
            S += __shfl_down(S, off);
        }
        if (ln == 0) {
            int o = ob + w * 4 + oo;
            float* po = out_p + bq * 128;
            if (ACC) {
                po[o] += M;
                po[64 + o] += S * (1.f / 512.f);
            } else {
                po[o] = M;
                po[64 + o] = S * (1.f / 512.f);
                vec_out[bq * 64 + o] = M;
            }
        }
    }
}

// ---------------- corre_binar: f, masks ----------------
__global__ __launch_bounds__(256) void corre_kernel(
    const float* __restrict__ x, const float* __restrict__ x0vec,
    const float* __restrict__ w_reduce, const int* __restrict__ idx8,
    float* __restrict__ fbuf, float* __restrict__ masks)
{
    __shared__ float sxv[64], sq[64], ss[512], sfk[512];
    int bq = blockIdx.x, tid = threadIdx.x;
    int row = src_row(bq);
    const float* Xb = x + (size_t)row * 32768;
    if (tid < 64) sxv[tid] = x0vec[bq * 64 + tid];
    __syncthreads();
    if (tid < 64) {
        float a = 0.f;
        for (int c = 0; c < 64; ++c) a += w_reduce[tid * 64 + c] * sxv[c];
        sq[tid] = a;
    }
    __syncthreads();
    for (int i = tid; i < 512; i += 256) {
        float a = 0.f;
        for (int c = 0; c < 64; ++c) a += sq[c] * Xb[c * 512 + i];
        a *= 0.125f;                    // 1/sqrt(64)
        ss[i] = a;
        fbuf[bq * 512 + i] = a;
    }
    __syncthreads();
    for (int i = tid; i < 512; i += 256) {
        float a = ss[i];
        const int* ip = idx8 + ((size_t)bq * 512 + i) * 16;
        for (int q = 0; q < 8; ++q) a += ss[ip[q]];
        sfk[i] = a;
    }
    masks[bq * 512 + tid] = 1.0f;
    masks[bq * 512 + tid + 256] = 1.0f;
    __syncthreads();
    if (tid == 0) {
        float best = sfk[0]; int bi = 0;
        for (int i = 1; i < 512; ++i) if (sfk[i] > best) { best = sfk[i]; bi = i; }
        masks[bq * 512 + bi] = 0.f;
        const int* ip = idx8 + ((size_t)bq * 512 + bi) * 16;
        for (int q = 0; q < 8; ++q) masks[bq * 512 + ip[q]] = 0.f;
    }
}

// ---------------- erase1 fused with prep: x1e -> h/l split + colnorms ----------------
__global__ __launch_bounds__(256) void erase1_kernel(
    const float* __restrict__ x, const float* __restrict__ masks,
    const float* __restrict__ fbuf,
    const float* __restrict__ w_e, const float* __restrict__ b_e,
    const float* __restrict__ g_e, const float* __restrict__ be_e,
    const float* __restrict__ m_e, const float* __restrict__ v_e,
    _Float16* __restrict__ H, _Float16* __restrict__ L, float* __restrict__ xn)
{
    __shared__ float sw[512];
    __shared__ float smk[512];
    __shared__ float red[256];
    __shared__ float sres[64];
    __shared__ float sy[64];
    __shared__ float lds[64 * 65];
    __shared__ float xnp[4 * 64];
    int bq = blockIdx.x, tid = threadIdx.x;
    int row = src_row(bq);
    const float* Xb = x + (size_t)row * 32768;
    float f0 = fbuf[bq * 512 + tid], f1 = fbuf[bq * 512 + tid + 256];
    float mk0 = masks[bq * 512 + tid], mk1 = masks[bq * 512 + tid + 256];
    smk[tid] = mk0; smk[tid + 256] = mk1;
    float s0 = f0 - (1.f - mk0) * 1e8f, s1 = f1 - (1.f - mk1) * 1e8f;
    red[tid] = fmaxf(s0, s1);
    __syncthreads();
    for (int off = 128; off >= 1; off >>= 1) {
        if (tid < off) red[tid] = fmaxf(red[tid], red[tid + off]);
        __syncthreads();
    }
    float mx = red[0];
    __syncthreads();
    float e0 = expf(s0 - mx), e1 = expf(s1 - mx);
    red[tid] = e0 + e1;
    __syncthreads();
    for (int off = 128; off >= 1; off >>= 1) {
        if (tid < off) red[tid] = red[tid] + red[tid + off];
        __syncthreads();
    }
    float inv = 1.f / red[0];
    __syncthreads();
    sw[tid] = e0 * inv; sw[tid + 256] = e1 * inv;
    __syncthreads();
    int c4 = tid >> 2, p4 = tid & 3;
    {
        float a = 0.f;
        const float* xr = Xb + c4 * 512 + p4 * 128;
        const float* wr = &sw[p4 * 128];
        for (int ii = 0; ii < 128; ++ii) a += xr[ii] * wr[ii];
        red[tid] = a;
    }
    __syncthreads();
    if (p4 == 0) sres[c4] = red[tid] + red[tid + 1] + red[tid + 2] + red[tid + 3];
    __syncthreads();
    if (tid < 64) {
        float a = b_e[tid];
        for (int cc = 0; cc < 64; ++cc) a += w_e[tid * 64 + cc] * sres[cc];
        float sc = g_e[tid] / sqrtf(v_e[tid] + EPS);
        sy[tid] = (a - m_e[tid]) * sc + be_e[tid];
    }
    // per col-tile: x1e = Xb*mask + sy -> fp16 split + colnorm
    for (int tt = 0; tt < 8; ++tt) {
        __syncthreads();                   // sy ready (tt=0); lds reusable (tt>0)
        for (int p = 0; p < 16; ++p) {
            int t = p * 256 + tid;
            int c = t >> 6, col = t & 63;
            float v = Xb[c * 512 + tt * 64 + col] * smk[tt * 64 + col] + sy[c];
            lds[c * 65 + col] = v;
        }
        __syncthreads();
        int col = tid & 63, g = tid >> 6;
        half8 hv[2], lv[2];
        float s = 0.f;
        #pragma unroll
        for (int k = 0; k < 16; ++k) {
            int c = g * 16 + k;
            float v = lds[c * 65 + col];
            _Float16 h = (_Float16)v;
            _Float16 lo = (_Float16)(v - (float)h);
            hv[k >> 3][k & 7] = h;
            lv[k >> 3][k & 7] = lo;
            s += v * v;
        }
        size_t obase = ((size_t)bq * 512 + tt * 64 + col) * 64 + g * 16;
        *(half8*)(H + obase) = hv[0];
        *(half8*)(H + obase + 8) = hv[1];
        *(half8*)(L + obase) = lv[0];
        *(half8*)(L + obase + 8) = lv[1];
        xnp[g * 64 + col] = s;
        __syncthreads();
        if (tid < 64)
            xn[bq * 512 + tt * 64 + tid] =
                xnp[tid] + xnp[64 + tid] + xnp[128 + tid] + xnp[192 + tid];
    }
}

extern "C" void kernel_launch(void* const* d_in, const int* in_sizes, int n_in,
                              void* d_out, int out_size, void* d_ws, size_t ws_size,
                              hipStream_t stream)
{
    const float* x        = (const float*)d_in[0];
    const float* w_reduce = (const float*)d_in[1];
    const float* w_erase  = (const float*)d_in[2];
    const float* b_erase  = (const float*)d_in[3];
    const float* g_erase  = (const float*)d_in[4];
    const float* be_erase = (const float*)d_in[5];
    const float* m_erase  = (const float*)d_in[6];
    const float* v_erase  = (const float*)d_in[7];
    const float* w0 = (const float*)d_in[8];
    const float* g0 = (const float*)d_in[9];
    const float* b0 = (const float*)d_in[10];
    const float* m0 = (const float*)d_in[11];
    const float* v0 = (const float*)d_in[12];
    const float* w1 = (const float*)d_in[13];
    const float* g1 = (const float*)d_in[14];
    const float* b1 = (const float*)d_in[15];
    const float* m1 = (const float*)d_in[16];
    const float* v1 = (const float*)d_in[17];
    float* out = (float*)d_out;
    char* ws = (char*)d_ws;

    // Layout (lifetime-overlaid):
    _Float16* h0 = (_Float16*)(ws);              // [0, 6.29M)   x0 / x1e high
    _Float16* l0 = (_Float16*)(ws + 6291456);    // [6.29, 12.58M)
    _Float16* h1 = (_Float16*)(ws + 12582912);   // [12.58, 18.87M)  x1seq high (dies after dual-knn)
    _Float16* l1 = (_Float16*)(ws + 18874368);   // [18.87, 25.17M)
    float* AB    = (float*)(ws + 12582912);      // [12.58, 37.75M)  overlays h1/l1 (written after dual-knn)
    int*   idxA  = (int*)(ws + 37748736);        // 3.15 MB
    int*   idx8  = (int*)(ws + 40894464);        // 3.15 MB
    float* xn0   = (float*)(ws + 44040192);      // 192 KB
    float* xn1   = (float*)(ws + 44236800);      // 192 KB
    float* y0vec = (float*)(ws + 44433408);      // 24 KB
    float* x0vec = (float*)(ws + 44457984);      // 24 KB
    float* fbuf  = (float*)(ws + 44482560);      // 192 KB
    float* masks = (float*)(ws + 44679168);      // 192 KB
    _Float16* wh0 = (_Float16*)(ws + 44875776);  // 16 KB
    _Float16* wl0 = (_Float16*)(ws + 44892160);  // 16 KB
    _Float16* wh1 = (_Float16*)(ws + 44908544);  // 16 KB
    _Float16* wl1 = (_Float16*)(ws + 44924928);  // 16 KB  (end ~44.94 MB)

    (void)in_sizes; (void)n_in; (void)out_size; (void)ws_size;

    // x0 = x + y0vec (folded into prep)
    erase0_kernel<<<96, 256, 0, stream>>>(x, w_erase, b_erase, g_erase, be_erase, m_erase, v_erase, y0vec);
    // fused prep for x0 (half 0), x1seq (half 1), + W' splits
    prep_kernel<<<1536, 256, 0, stream>>>(x, y0vec, h0, l0, xn0, h1, l1, xn1,
                                          w0, w1, wh0, wl0, wh1, wl1);
    // fused kNN: k=10 on x0 -> idxA ; k=8 on x1seq -> idx8
    knn_kernel<<<1536, 256, 0, stream>>>(h0, l0, xn0, idxA, 10, h1, l1, xn1, idx8, 8);
    // branch 0 (gemm writes AB over dead h1/l1)
    gemm_mfma_kernel<<<768, 256, 0, stream>>>(h0, l0, wh0, wl0, AB);
    branch_reduce_kernel<0><<<dim3(96, 4), 256, 0, stream>>>(AB, idxA, g0, b0, m0, v0, out, x0vec);
    // corre_binar on x1seq
    corre_kernel<<<96, 256, 0, stream>>>(x, x0vec, w_reduce, idx8, fbuf, masks);
    // x1e = erase(x1seq, masks, f): rewrite h0/l0/xn0 in place
    erase1_kernel<<<96, 256, 0, stream>>>(x, masks, fbuf, w_erase, b_erase, g_erase, be_erase, m_erase, v_erase,
                                          h0, l0, xn0);
    // branch 1
    knn_kernel<<<768, 256, 0, stream>>>(h0, l0, xn0, idxA, 10, h0, l0, xn0, idxA, 10);
    gemm_mfma_kernel<<<768, 256, 0, stream>>>(h0, l0, wh1, wl1, AB);
    branch_reduce_kernel<1><<<dim3(96, 4), 256, 0, stream>>>(AB, idxA, g1, b1, m1, v1, out, nullptr);
}

// Round 8
// 393.798 us; speedup vs baseline: 1.0685x; 1.0685x over previous
//
#include <hip/hip_runtime.h>
#include <math.h>

#define EPS 1e-5f

typedef _Float16 half8 __attribute__((ext_vector_type(8)));
typedef float f32x4 __attribute__((ext_vector_type(4)));

// bq in [0,96): b = bq/12, t = bq%12; x1seq row = b*12 + min(t+1, 11)
__device__ __forceinline__ int src_row(int bq) {
    int b = bq / 12, t = bq - b * 12;
    int t2 = (t + 1 < 12) ? (t + 1) : 11;
    return b * 12 + t2;
}

// ---------------- erase0: y0vec[bq][o] = BN(W_e @ mean_n(x) + b_e) ----------------
__global__ __launch_bounds__(256) void erase0_kernel(
    const float* __restrict__ x, const float* __restrict__ w_e,
    const float* __restrict__ b_e, const float* __restrict__ g_e,
    const float* __restrict__ be_e, const float* __restrict__ m_e,
    const float* __restrict__ v_e, float* __restrict__ y0vec)
{
    __shared__ float part[256];
    __shared__ float res[64];
    int bq = blockIdx.x, tid = threadIdx.x;
    int c = tid >> 2, p = tid & 3;
    const float* xb = x + (size_t)bq * 32768 + c * 512 + p * 128;
    float acc = 0.f;
    for (int ii = 0; ii < 128; ii += 4) {
        float4 v = *(const float4*)(xb + ii);
        acc += v.x + v.y + v.z + v.w;
    }
    part[tid] = acc;
    __syncthreads();
    if (p == 0) res[c] = (part[tid] + part[tid+1] + part[tid+2] + part[tid+3]) * (1.f/512.f);
    __syncthreads();
    if (tid < 64) {
        float a = b_e[tid];
        for (int cc = 0; cc < 64; ++cc) a += w_e[tid*64+cc] * res[cc];
        float s = g_e[tid] / sqrtf(v_e[tid] + EPS);
        y0vec[bq*64 + tid] = (a - m_e[tid]) * s + be_e[tid];
    }
}

// ---------------- prep dual + W' split ----------------
__global__ __launch_bounds__(256) void prep_kernel(
    const float* __restrict__ X, const float* __restrict__ vec,
    _Float16* __restrict__ H0, _Float16* __restrict__ L0, float* __restrict__ xn0,
    _Float16* __restrict__ H1, _Float16* __restrict__ L1, float* __restrict__ xn1,
    const float* __restrict__ w0, const float* __restrict__ w1,
    _Float16* __restrict__ wh0, _Float16* __restrict__ wl0,
    _Float16* __restrict__ wh1, _Float16* __restrict__ wl1)
{
    __shared__ float lds[64 * 65];
    __shared__ float xnp[4 * 64];
    int raw = blockIdx.x;
    int bq = raw % 96;
    int q = raw / 96;
    int ct = q & 7, half = q >> 3;
    int row = half ? src_row(bq) : bq;
    _Float16* H = half ? H1 : H0;
    _Float16* L = half ? L1 : L0;
    float* xn = half ? xn1 : xn0;
    const float* vp = half ? nullptr : vec;
    const float* Xb = X + (size_t)row * 32768 + ct * 64;
    int tid = threadIdx.x;
    for (int p = 0; p < 16; ++p) {
        int t = p * 256 + tid;
        int c = t >> 6, col = t & 63;
        float v = Xb[c * 512 + col];
        if (vp) v += vp[bq * 64 + c];
        lds[c * 65 + col] = v;
    }
    __syncthreads();
    int col = tid & 63, g = tid >> 6;
    half8 hv[2], lv[2];
    float s = 0.f;
    #pragma unroll
    for (int k = 0; k < 16; ++k) {
        int c = g * 16 + k;
        float v = lds[c * 65 + col];
        _Float16 h = (_Float16)v;
        _Float16 lo = (_Float16)(v - (float)h);
        hv[k >> 3][k & 7] = h;
        lv[k >> 3][k & 7] = lo;
        s += v * v;
    }
    size_t obase = ((size_t)bq * 512 + ct * 64 + col) * 64 + g * 16;
    *(half8*)(H + obase) = hv[0];
    *(half8*)(H + obase + 8) = hv[1];
    *(half8*)(L + obase) = lv[0];
    *(half8*)(L + obase + 8) = lv[1];
    xnp[g * 64 + col] = s;
    __syncthreads();
    if (tid < 64)
        xn[bq * 512 + ct * 64 + tid] =
            xnp[tid] + xnp[64 + tid] + xnp[128 + tid] + xnp[192 + tid];
    if (raw < 2) {
        const float* W = raw ? w1 : w0;
        _Float16* WH = raw ? wh1 : wh0;
        _Float16* WL = raw ? wl1 : wl0;
        for (int t = tid; t < 8192; t += 256) {
            int o = t >> 6, c = t & 63;
            float v = (o < 64) ? W[o * 128 + c]
                               : (W[(o - 64) * 128 + 64 + c] - W[(o - 64) * 128 + c]);
            _Float16 h = (_Float16)v;
            WH[t] = h;
            WL[t] = (_Float16)(v - (float)h);
        }
    }
}

// ---------------- kNN v4: MFMA + value-only sort (uint keys, 4-bit slot code) ----------------
// Keys: sign-flipped fp32 bits, low 4 mantissa bits replaced by (15 - slot) so that
// within a tile larger key = larger score, tie -> smaller j. Perturbation <= 2^-19 rel.
// Running top-10 (keys + exact int j) per quad; merged 4-way at the end.
__global__ __launch_bounds__(256) void knn_kernel(
    const _Float16* __restrict__ H0, const _Float16* __restrict__ L0,
    const float* __restrict__ xn0, int* __restrict__ idx0, int k0,
    const _Float16* __restrict__ H1, const _Float16* __restrict__ L1,
    const float* __restrict__ xn1, int* __restrict__ idx1, int k1)
{
    __shared__ unsigned ldsMV[4][64 * 11];   // per wave: 64 lists x 10 keys, pad 11
    __shared__ int      ldsMJ[4][64 * 11];
    int raw = blockIdx.x;
    int bq = raw % 96;
    int q = raw / 96;
    int itile = q & 7, half = q >> 3;
    const _Float16* H = half ? H1 : H0;
    const _Float16* L = half ? L1 : L0;
    const float* xn = half ? xn1 : xn0;
    int* idx_out = half ? idx1 : idx0;
    int K = half ? k1 : k0;
    int tid = threadIdx.x, w = tid >> 6, l = tid & 63;
    int lane16 = l & 15, quad = l >> 4;
    const size_t base = (size_t)bq * 512 * 64;
    int irow = itile * 64 + w * 16 + lane16;
    const _Float16* Hi = H + base + (size_t)irow * 64 + quad * 8;
    const _Float16* Li = L + base + (size_t)irow * 64 + quad * 8;
    half8 Bh0 = *(const half8*)(Hi);
    half8 Bh1 = *(const half8*)(Hi + 32);
    half8 Bl0 = *(const half8*)(Li);
    half8 Bl1 = *(const half8*)(Li + 32);

    unsigned kv[10]; int kj[10];           // ascending keys (kv[9] = best)
    #pragma unroll
    for (int qq = 0; qq < 10; ++qq) { kv[qq] = 0u; kj[qq] = 0; }

    auto casu = [](unsigned& a, unsigned& b) {
        unsigned mn = a < b ? a : b;
        unsigned mx = a < b ? b : a;
        a = mn; b = mx;
    };
    auto cas_kj = [](unsigned& ka, int& ja, unsigned& kb, int& jb2) {
        bool sw = ka > kb;
        unsigned tk = ka; int tj = ja;
        ka = sw ? kb : ka; ja = sw ? jb2 : ja;
        kb = sw ? tk : kb; jb2 = sw ? tj : jb2;
    };

    const float* xnb = xn + bq * 512;
    for (int jt = 0; jt < 8; ++jt) {
        unsigned d[16];
        #pragma unroll
        for (int g = 0; g < 4; ++g) {
            int jrow = jt * 64 + g * 16 + lane16;
            const _Float16* Hj = H + base + (size_t)jrow * 64 + quad * 8;
            const _Float16* Lj = L + base + (size_t)jrow * 64 + quad * 8;
            half8 Ah0 = *(const half8*)(Hj);
            half8 Ah1 = *(const half8*)(Hj + 32);
            half8 Al0 = *(const half8*)(Lj);
            half8 Al1 = *(const half8*)(Lj + 32);
            f32x4 acc = {0.f, 0.f, 0.f, 0.f};
            acc = __builtin_amdgcn_mfma_f32_16x16x32_f16(Ah0, Bh0, acc, 0, 0, 0);
            acc = __builtin_amdgcn_mfma_f32_16x16x32_f16(Ah1, Bh1, acc, 0, 0, 0);
            acc = __builtin_amdgcn_mfma_f32_16x16x32_f16(Al0, Bh0, acc, 0, 0, 0);
            acc = __builtin_amdgcn_mfma_f32_16x16x32_f16(Al1, Bh1, acc, 0, 0, 0);
            acc = __builtin_amdgcn_mfma_f32_16x16x32_f16(Ah0, Bl0, acc, 0, 0, 0);
            acc = __builtin_amdgcn_mfma_f32_16x16x32_f16(Ah1, Bl1, acc, 0, 0, 0);
            int jb = jt * 64 + g * 16 + quad * 4;   // lane holds j = jb..jb+3
            float4 xn4 = *(const float4*)&xnb[jb];
            #pragma unroll
            for (int r = 0; r < 4; ++r) {
                float sc = 2.f * acc[r] - (r == 0 ? xn4.x : r == 1 ? xn4.y : r == 2 ? xn4.z : xn4.w);
                int bi = __float_as_int(sc);
                unsigned u = (unsigned)(bi ^ ((bi >> 31) | 0x80000000));
                int slot = g * 4 + r;               // j strictly increasing in slot
                d[slot] = (u & 0xFFFFFFF0u) | (unsigned)(15 - slot);
            }
        }
        // Batcher odd-even mergesort-16 ascending, value-only (2-inst CAS)
        #pragma unroll
        for (int p = 1; p < 16; p <<= 1) {
            #pragma unroll
            for (int k = p; k >= 1; k >>= 1) {
                #pragma unroll
                for (int j = k & (p - 1); j + k < 16; j += 2 * k) {
                    #pragma unroll
                    for (int i = 0; i < k; ++i) {
                        if ((i + j + k < 16) &&
                            ((i + j) / (2 * p) == (i + j + k) / (2 * p)))
                            casu(d[i + j], d[i + j + k]);
                    }
                }
            }
        }
        // top-10 of union: pair kv[i] (asc) with d[15-i] (desc tail), decode j for taken
        #pragma unroll
        for (int i = 0; i < 10; ++i) {
            unsigned dv = d[15 - i];
            int code = 15 - (int)(dv & 15u);
            int jnew = jt * 64 + (code >> 2) * 16 + quad * 4 + (code & 3);
            bool keep = kv[i] >= dv;
            kj[i] = keep ? kj[i] : jnew;
            kv[i] = keep ? kv[i] : dv;
        }
        // clean bitonic (V-shaped) length-10: strides 8, then merge-8, then (8,9)
        cas_kj(kv[0], kj[0], kv[8], kj[8]);
        cas_kj(kv[1], kj[1], kv[9], kj[9]);
        cas_kj(kv[0], kj[0], kv[4], kj[4]);
        cas_kj(kv[1], kj[1], kv[5], kj[5]);
        cas_kj(kv[2], kj[2], kv[6], kj[6]);
        cas_kj(kv[3], kj[3], kv[7], kj[7]);
        cas_kj(kv[0], kj[0], kv[2], kj[2]);
        cas_kj(kv[1], kj[1], kv[3], kj[3]);
        cas_kj(kv[4], kj[4], kv[6], kj[6]);
        cas_kj(kv[5], kj[5], kv[7], kj[7]);
        cas_kj(kv[0], kj[0], kv[1], kj[1]);
        cas_kj(kv[2], kj[2], kv[3], kj[3]);
        cas_kj(kv[4], kj[4], kv[5], kj[5]);
        cas_kj(kv[6], kj[6], kv[7], kj[7]);
        cas_kj(kv[8], kj[8], kv[9], kj[9]);
    }
    // dump sorted-10 per quad, merge 4 lists per row (key desc, tie: smaller j)
    #pragma unroll
    for (int qq = 0; qq < 10; ++qq) {
        ldsMV[w][(lane16 * 4 + quad) * 11 + qq] = kv[qq];
        ldsMJ[w][(lane16 * 4 + quad) * 11 + qq] = kj[qq];
    }
    __syncthreads();
    if (quad == 0) {
        const unsigned* MV = &ldsMV[w][lane16 * 44];
        const int*      MJ = &ldsMJ[w][lane16 * 44];
        int p0 = 9, p1 = 9, p2 = 9, p3 = 9;
        int* op = idx_out + ((size_t)bq * 512 + irow) * 16;
        for (int t = 0; t < K; ++t) {
            unsigned bv = 0u; int bj = 0x7fffffff; int bc = -1;
            { unsigned v = MV[p0]; int j = MJ[p0];
              if (v > bv || (v == bv && j < bj)) { bv = v; bj = j; bc = 0; } }
            { unsigned v = MV[11 + p1]; int j = MJ[11 + p1];
              if (v > bv || (v == bv && j < bj)) { bv = v; bj = j; bc = 1; } }
            { unsigned v = MV[22 + p2]; int j = MJ[22 + p2];
              if (v > bv || (v == bv && j < bj)) { bv = v; bj = j; bc = 2; } }
            { unsigned v = MV[33 + p3]; int j = MJ[33 + p3];
              if (v > bv || (v == bv && j < bj)) { bv = v; bj = j; bc = 3; } }
            if (bc == 0) --p0; else if (bc == 1) --p1; else if (bc == 2) --p2; else --p3;
            op[t] = bj;
        }
    }
}

// ---------------- fused branch: MFMA A,B into LDS + gather-reduce, grid (96,2) ----------------
// Block handles 32 o's (ob = blockIdx.y*32). Phase1: 4 waves compute 4 row-tiles
// (2 A-tiles rows ob.., 2 B-tiles rows 64+ob..) into ldsAB[64][512]. Phase2: gather-reduce.
template<int ACC>
__global__ __launch_bounds__(256) void fused_branch_kernel(
    const _Float16* __restrict__ H, const _Float16* __restrict__ L,
    const _Float16* __restrict__ WH, const _Float16* __restrict__ WL,
    const int* __restrict__ idx,
    const float* __restrict__ g, const float* __restrict__ bb,
    const float* __restrict__ mm, const float* __restrict__ vv,
    float* __restrict__ out_p, float* __restrict__ vec_out)
{
    __shared__ float ldsAB[64 * 512];      // 128 KB: rows 0..31 = A(ob..), 32..63 = B(64+ob..)
    __shared__ int   ldsIdx[512 * 10];     // 20 KB
    int bq = blockIdx.x, ob = blockIdx.y * 32;
    int tid = threadIdx.x, w = tid >> 6, l = tid & 63;
    int lane16 = l & 15, quad = l >> 4;
    const size_t xbase = (size_t)bq * 32768;
    for (int p = 0; p < 20; ++p) {
        int t = p * 256 + tid;
        int i = t / 10, q = t - i * 10;
        ldsIdx[t] = idx[((size_t)bq * 512 + i) * 16 + q];
    }
    // phase 1: wave w computes W' row-tile: w<2 -> A rows ob+w*16.., else B rows 64+ob+(w-2)*16..
    {
        int wrow = (w < 2) ? (ob + w * 16) : (64 + ob + (w - 2) * 16);
        size_t woff = (size_t)(wrow + lane16) * 64 + quad * 8;
        half8 Ah0 = *(const half8*)(WH + woff);
        half8 Ah1 = *(const half8*)(WH + woff + 32);
        half8 Al0 = *(const half8*)(WL + woff);
        half8 Al1 = *(const half8*)(WL + woff + 32);
        for (int it = 0; it < 32; ++it) {
            size_t off = xbase + (size_t)(it * 16 + lane16) * 64 + quad * 8;
            half8 Xh0 = *(const half8*)(H + off);
            half8 Xh1 = *(const half8*)(H + off + 32);
            half8 Xl0 = *(const half8*)(L + off);
            half8 Xl1 = *(const half8*)(L + off + 32);
            f32x4 acc = {0.f, 0.f, 0.f, 0.f};
            acc = __builtin_amdgcn_mfma_f32_16x16x32_f16(Ah0, Xh0, acc, 0, 0, 0);
            acc = __builtin_amdgcn_mfma_f32_16x16x32_f16(Ah1, Xh1, acc, 0, 0, 0);
            acc = __builtin_amdgcn_mfma_f32_16x16x32_f16(Ah0, Xl0, acc, 0, 0, 0);
            acc = __builtin_amdgcn_mfma_f32_16x16x32_f16(Ah1, Xl1, acc, 0, 0, 0);
            acc = __builtin_amdgcn_mfma_f32_16x16x32_f16(Al0, Xh0, acc, 0, 0, 0);
            acc = __builtin_amdgcn_mfma_f32_16x16x32_f16(Al1, Xh1, acc, 0, 0, 0);
            #pragma unroll
            for (int r = 0; r < 4; ++r)
                ldsAB[(w * 16 + quad * 4 + r) * 512 + it * 16 + lane16] = acc[r];
        }
    }
    __syncthreads();
    // phase 2: wave w reduces o's = ob + w*8 + (0..7); A row = w*8+oo, B row = 32+w*8+oo
    float ssr[8], str[8];
    #pragma unroll
    for (int oo = 0; oo < 8; ++oo) {
        int o = ob + w * 8 + oo;
        float sc = g[o] / sqrtf(vv[o] + EPS);
        ssr[oo] = sc;
        str[oo] = bb[o] - mm[o] * sc;
    }
    float omax[8], osum[8];
    #pragma unroll
    for (int oo = 0; oo < 8; ++oo) { omax[oo] = -3.4e38f; osum[oo] = 0.f; }
    const float* Aw = ldsAB + (w * 8) * 512;
    const float* Bw = ldsAB + (32 + w * 8) * 512;
    for (int s = 0; s < 8; ++s) {
        int i = l + 64 * s;
        int idr[10];
        const int* ip = &ldsIdx[i * 10];
        #pragma unroll
        for (int q = 0; q < 10; ++q) idr[q] = ip[q];
        #pragma unroll
        for (int oo = 0; oo < 8; ++oo) {
            const float* Ao = Aw + oo * 512;
            float mx = Ao[idr[0]];
            #pragma unroll
            for (int q = 1; q < 10; ++q) mx = fmaxf(mx, Ao[idr[q]]);
            float val = (mx + Bw[oo * 512 + i]) * ssr[oo] + str[oo];
            float y = val > 0.f ? val : 0.2f * val;
            omax[oo] = fmaxf(omax[oo], y);
            osum[oo] += y;
        }
    }
    #pragma unroll
    for (int oo = 0; oo < 8; ++oo) {
        float M = omax[oo], S = osum[oo];
        #pragma unroll
        for (int off = 32; off >= 1; off >>= 1) {
            M = fmaxf(M, __shfl_down(M, off));
            S += __shfl_down(S, off);
        }
        if (l == 0) {
            int o = ob + w * 8 + oo;
            float* po = out_p + bq * 128;
            if (ACC) {
                po[o] += M;
                po[64 + o] += S * (1.f / 512.f);
            } else {
                po[o] = M;
                po[64 + o] = S * (1.f / 512.f);
                vec_out[bq * 64 + o] = M;
            }
        }
    }
}

// ---------------- corre_binar: f, masks ----------------
__global__ __launch_bounds__(256) void corre_kernel(
    const float* __restrict__ x, const float* __restrict__ x0vec,
    const float* __restrict__ w_reduce, const int* __restrict__ idx8,
    float* __restrict__ fbuf, float* __restrict__ masks)
{
    __shared__ float sxv[64], sq[64], ss[512], sfk[512];
    int bq = blockIdx.x, tid = threadIdx.x;
    int row = src_row(bq);
    const float* Xb = x + (size_t)row * 32768;
    if (tid < 64) sxv[tid] = x0vec[bq * 64 + tid];
    __syncthreads();
    if (tid < 64) {
        float a = 0.f;
        for (int c = 0; c < 64; ++c) a += w_reduce[tid * 64 + c] * sxv[c];
        sq[tid] = a;
    }
    __syncthreads();
    for (int i = tid; i < 512; i += 256) {
        float a = 0.f;
        for (int c = 0; c < 64; ++c) a += sq[c] * Xb[c * 512 + i];
        a *= 0.125f;
        ss[i] = a;
        fbuf[bq * 512 + i] = a;
    }
    __syncthreads();
    for (int i = tid; i < 512; i += 256) {
        float a = ss[i];
        const int* ip = idx8 + ((size_t)bq * 512 + i) * 16;
        for (int q = 0; q < 8; ++q) a += ss[ip[q]];
        sfk[i] = a;
    }
    masks[bq * 512 + tid] = 1.0f;
    masks[bq * 512 + tid + 256] = 1.0f;
    __syncthreads();
    if (tid == 0) {
        float best = sfk[0]; int bi = 0;
        for (int i = 1; i < 512; ++i) if (sfk[i] > best) { best = sfk[i]; bi = i; }
        masks[bq * 512 + bi] = 0.f;
        const int* ip = idx8 + ((size_t)bq * 512 + bi) * 16;
        for (int q = 0; q < 8; ++q) masks[bq * 512 + ip[q]] = 0.f;
    }
}

// ---------------- erase1 fused with prep: x1e -> h/l split + colnorms ----------------
__global__ __launch_bounds__(256) void erase1_kernel(
    const float* __restrict__ x, const float* __restrict__ masks,
    const float* __restrict__ fbuf,
    const float* __restrict__ w_e, const float* __restrict__ b_e,
    const float* __restrict__ g_e, const float* __restrict__ be_e,
    const float* __restrict__ m_e, const float* __restrict__ v_e,
    _Float16* __restrict__ H, _Float16* __restrict__ L, float* __restrict__ xn)
{
    __shared__ float sw[512];
    __shared__ float smk[512];
    __shared__ float red[256];
    __shared__ float sres[64];
    __shared__ float sy[64];
    __shared__ float lds[64 * 65];
    __shared__ float xnp[4 * 64];
    int bq = blockIdx.x, tid = threadIdx.x;
    int row = src_row(bq);
    const float* Xb = x + (size_t)row * 32768;
    float f0 = fbuf[bq * 512 + tid], f1 = fbuf[bq * 512 + tid + 256];
    float mk0 = masks[bq * 512 + tid], mk1 = masks[bq * 512 + tid + 256];
    smk[tid] = mk0; smk[tid + 256] = mk1;
    float s0 = f0 - (1.f - mk0) * 1e8f, s1 = f1 - (1.f - mk1) * 1e8f;
    red[tid] = fmaxf(s0, s1);
    __syncthreads();
    for (int off = 128; off >= 1; off >>= 1) {
        if (tid < off) red[tid] = fmaxf(red[tid], red[tid + off]);
        __syncthreads();
    }
    float mx = red[0];
    __syncthreads();
    float e0 = expf(s0 - mx), e1 = expf(s1 - mx);
    red[tid] = e0 + e1;
    __syncthreads();
    for (int off = 128; off >= 1; off >>= 1) {
        if (tid < off) red[tid] = red[tid] + red[tid + off];
        __syncthreads();
    }
    float inv = 1.f / red[0];
    __syncthreads();
    sw[tid] = e0 * inv; sw[tid + 256] = e1 * inv;
    __syncthreads();
    int c4 = tid >> 2, p4 = tid & 3;
    {
        float a = 0.f;
        const float* xr = Xb + c4 * 512 + p4 * 128;
        const float* wr = &sw[p4 * 128];
        for (int ii = 0; ii < 128; ++ii) a += xr[ii] * wr[ii];
        red[tid] = a;
    }
    __syncthreads();
    if (p4 == 0) sres[c4] = red[tid] + red[tid + 1] + red[tid + 2] + red[tid + 3];
    __syncthreads();
    if (tid < 64) {
        float a = b_e[tid];
        for (int cc = 0; cc < 64; ++cc) a += w_e[tid * 64 + cc] * sres[cc];
        float sc = g_e[tid] / sqrtf(v_e[tid] + EPS);
        sy[tid] = (a - m_e[tid]) * sc + be_e[tid];
    }
    for (int tt = 0; tt < 8; ++tt) {
        __syncthreads();
        for (int p = 0; p < 16; ++p) {
            int t = p * 256 + tid;
            int c = t >> 6, col = t & 63;
            float v = Xb[c * 512 + tt * 64 + col] * smk[tt * 64 + col] + sy[c];
            lds[c * 65 + col] = v;
        }
        __syncthreads();
        int col = tid & 63, g = tid >> 6;
        half8 hv[2], lv[2];
        float s = 0.f;
        #pragma unroll
        for (int k = 0; k < 16; ++k) {
            int c = g * 16 + k;
            float v = lds[c * 65 + col];
            _Float16 h = (_Float16)v;
            _Float16 lo = (_Float16)(v - (float)h);
            hv[k >> 3][k & 7] = h;
            lv[k >> 3][k & 7] = lo;
            s += v * v;
        }
        size_t obase = ((size_t)bq * 512 + tt * 64 + col) * 64 + g * 16;
        *(half8*)(H + obase) = hv[0];
        *(half8*)(H + obase + 8) = hv[1];
        *(half8*)(L + obase) = lv[0];
        *(half8*)(L + obase + 8) = lv[1];
        xnp[g * 64 + col] = s;
        __syncthreads();
        if (tid < 64)
            xn[bq * 512 + tt * 64 + tid] =
                xnp[tid] + xnp[64 + tid] + xnp[128 + tid] + xnp[192 + tid];
    }
}

extern "C" void kernel_launch(void* const* d_in, const int* in_sizes, int n_in,
                              void* d_out, int out_size, void* d_ws, size_t ws_size,
                              hipStream_t stream)
{
    const float* x        = (const float*)d_in[0];
    const float* w_reduce = (const float*)d_in[1];
    const float* w_erase  = (const float*)d_in[2];
    const float* b_erase  = (const float*)d_in[3];
    const float* g_erase  = (const float*)d_in[4];
    const float* be_erase = (const float*)d_in[5];
    const float* m_erase  = (const float*)d_in[6];
    const float* v_erase  = (const float*)d_in[7];
    const float* w0 = (const float*)d_in[8];
    const float* g0 = (const float*)d_in[9];
    const float* b0 = (const float*)d_in[10];
    const float* m0 = (const float*)d_in[11];
    const float* v0 = (const float*)d_in[12];
    const float* w1 = (const float*)d_in[13];
    const float* g1 = (const float*)d_in[14];
    const float* b1 = (const float*)d_in[15];
    const float* m1 = (const float*)d_in[16];
    const float* v1 = (const float*)d_in[17];
    float* out = (float*)d_out;
    char* ws = (char*)d_ws;

    _Float16* h0 = (_Float16*)(ws);              // 6.29 MB  x0 / x1e high
    _Float16* l0 = (_Float16*)(ws + 6291456);    // 6.29 MB
    _Float16* h1 = (_Float16*)(ws + 12582912);   // 6.29 MB  x1seq high
    _Float16* l1 = (_Float16*)(ws + 18874368);   // 6.29 MB
    int*   idxA  = (int*)(ws + 37748736);        // 3.15 MB
    int*   idx8  = (int*)(ws + 40894464);        // 3.15 MB
    float* xn0   = (float*)(ws + 44040192);      // 192 KB
    float* xn1   = (float*)(ws + 44236800);      // 192 KB
    float* y0vec = (float*)(ws + 44433408);      // 24 KB
    float* x0vec = (float*)(ws + 44457984);      // 24 KB
    float* fbuf  = (float*)(ws + 44482560);      // 192 KB
    float* masks = (float*)(ws + 44679168);      // 192 KB
    _Float16* wh0 = (_Float16*)(ws + 44875776);  // 16 KB
    _Float16* wl0 = (_Float16*)(ws + 44892160);  // 16 KB
    _Float16* wh1 = (_Float16*)(ws + 44908544);  // 16 KB
    _Float16* wl1 = (_Float16*)(ws + 44924928);  // 16 KB

    (void)in_sizes; (void)n_in; (void)out_size; (void)ws_size;

    erase0_kernel<<<96, 256, 0, stream>>>(x, w_erase, b_erase, g_erase, be_erase, m_erase, v_erase, y0vec);
    prep_kernel<<<1536, 256, 0, stream>>>(x, y0vec, h0, l0, xn0, h1, l1, xn1,
                                          w0, w1, wh0, wl0, wh1, wl1);
    knn_kernel<<<1536, 256, 0, stream>>>(h0, l0, xn0, idxA, 10, h1, l1, xn1, idx8, 8);
    fused_branch_kernel<0><<<dim3(96, 2), 256, 0, stream>>>(h0, l0, wh0, wl0, idxA,
                                                            g0, b0, m0, v0, out, x0vec);
    corre_kernel<<<96, 256, 0, stream>>>(x, x0vec, w_reduce, idx8, fbuf, masks);
    erase1_kernel<<<96, 256, 0, stream>>>(x, masks, fbuf, w_erase, b_erase, g_erase, be_erase, m_erase, v_erase,
                                          h0, l0, xn0);
    knn_kernel<<<768, 256, 0, stream>>>(h0, l0, xn0, idxA, 10, h0, l0, xn0, idxA, 10);
    fused_branch_kernel<1><<<dim3(96, 2), 256, 0, stream>>>(h0, l0, wh1, wl1, idxA,
                                                            g1, b1, m1, v1, out, nullptr);
}

// Round 9
// 317.109 us; speedup vs baseline: 1.3269x; 1.2418x over previous
//
#include <hip/hip_runtime.h>
#include <math.h>

#define EPS 1e-5f

typedef _Float16 half8 __attribute__((ext_vector_type(8)));
typedef float f32x4 __attribute__((ext_vector_type(4)));

// H/L global layout per bq: [tile(8)][chunk(8)][row(64)] x 8 halves (16B units).
// unit(row, ch) = (tile*8 + ch/8)*64 + row%64 ; halves offset = unit*8 + ch%8.

// bq in [0,96): b = bq/12, t = bq%12; x1seq row = b*12 + min(t+1, 11)
__device__ __forceinline__ int src_row(int bq) {
    int b = bq / 12, t = bq - b * 12;
    int t2 = (t + 1 < 12) ? (t + 1) : 11;
    return b * 12 + t2;
}

// ---------------- erase0: y0vec[bq][o] = BN(W_e @ mean_n(x) + b_e) ----------------
__global__ __launch_bounds__(256) void erase0_kernel(
    const float* __restrict__ x, const float* __restrict__ w_e,
    const float* __restrict__ b_e, const float* __restrict__ g_e,
    const float* __restrict__ be_e, const float* __restrict__ m_e,
    const float* __restrict__ v_e, float* __restrict__ y0vec)
{
    __shared__ float part[256];
    __shared__ float res[64];
    int bq = blockIdx.x, tid = threadIdx.x;
    int c = tid >> 2, p = tid & 3;
    const float* xb = x + (size_t)bq * 32768 + c * 512 + p * 128;
    float acc = 0.f;
    for (int ii = 0; ii < 128; ii += 4) {
        float4 v = *(const float4*)(xb + ii);
        acc += v.x + v.y + v.z + v.w;
    }
    part[tid] = acc;
    __syncthreads();
    if (p == 0) res[c] = (part[tid] + part[tid+1] + part[tid+2] + part[tid+3]) * (1.f/512.f);
    __syncthreads();
    if (tid < 64) {
        float a = b_e[tid];
        for (int cc = 0; cc < 64; ++cc) a += w_e[tid*64+cc] * res[cc];
        float s = g_e[tid] / sqrtf(v_e[tid] + EPS);
        y0vec[bq*64 + tid] = (a - m_e[tid]) * s + be_e[tid];
    }
}

// ---------------- prep dual + W' split (chunk layout) ----------------
__global__ __launch_bounds__(256) void prep_kernel(
    const float* __restrict__ X, const float* __restrict__ vec,
    _Float16* __restrict__ H0, _Float16* __restrict__ L0, float* __restrict__ xn0,
    _Float16* __restrict__ H1, _Float16* __restrict__ L1, float* __restrict__ xn1,
    const float* __restrict__ w0, const float* __restrict__ w1,
    _Float16* __restrict__ wh0, _Float16* __restrict__ wl0,
    _Float16* __restrict__ wh1, _Float16* __restrict__ wl1)
{
    __shared__ float lds[64 * 65];
    __shared__ float xnp[4 * 64];
    int raw = blockIdx.x;
    int bq = raw % 96;
    int q = raw / 96;
    int ct = q & 7, half = q >> 3;
    int row = half ? src_row(bq) : bq;
    _Float16* H = half ? H1 : H0;
    _Float16* L = half ? L1 : L0;
    float* xn = half ? xn1 : xn0;
    const float* vp = half ? nullptr : vec;
    const float* Xb = X + (size_t)row * 32768 + ct * 64;
    int tid = threadIdx.x;
    for (int p = 0; p < 16; ++p) {
        int t = p * 256 + tid;
        int c = t >> 6, col = t & 63;
        float v = Xb[c * 512 + col];
        if (vp) v += vp[bq * 64 + c];
        lds[c * 65 + col] = v;
    }
    __syncthreads();
    int col = tid & 63, g = tid >> 6;
    half8 hv[2], lv[2];
    float s = 0.f;
    #pragma unroll
    for (int k = 0; k < 16; ++k) {
        int c = g * 16 + k;
        float v = lds[c * 65 + col];
        _Float16 h = (_Float16)v;
        _Float16 lo = (_Float16)(v - (float)h);
        hv[k >> 3][k & 7] = h;
        lv[k >> 3][k & 7] = lo;
        s += v * v;
    }
    // chunk layout: hv[0] -> chunk 2g, hv[1] -> chunk 2g+1 of tile ct, row col
    size_t obase = (size_t)bq * 32768 + ((size_t)(ct * 8 + 2 * g) * 64 + col) * 8;
    *(half8*)(H + obase) = hv[0];
    *(half8*)(H + obase + 512) = hv[1];
    *(half8*)(L + obase) = lv[0];
    *(half8*)(L + obase + 512) = lv[1];
    xnp[g * 64 + col] = s;
    __syncthreads();
    if (tid < 64)
        xn[bq * 512 + ct * 64 + tid] =
            xnp[tid] + xnp[64 + tid] + xnp[128 + tid] + xnp[192 + tid];
    if (raw < 2) {
        const float* W = raw ? w1 : w0;
        _Float16* WH = raw ? wh1 : wh0;
        _Float16* WL = raw ? wl1 : wl0;
        for (int t = tid; t < 8192; t += 256) {
            int o = t >> 6, c = t & 63;
            float v = (o < 64) ? W[o * 128 + c]
                               : (W[(o - 64) * 128 + 64 + c] - W[(o - 64) * 128 + c]);
            _Float16 h = (_Float16)v;
            WH[t] = h;
            WL[t] = (_Float16)(v - (float)h);
        }
    }
}

// ---------------- kNN v5: LDS-staged j-tiles + MFMA + value-only sort ----------------
// Per jt: block cooperatively stages the 16KB j-tile into LDS (linear float4 both
// sides, next tile prefetched into regs during compute); all 4 waves read their
// fragments from LDS (consecutive b128, conflict-free). Selection as in R8.
__global__ __launch_bounds__(256, 5) void knn_kernel(
    const _Float16* __restrict__ H0, const _Float16* __restrict__ L0,
    const float* __restrict__ xn0, int* __restrict__ idx0, int k0,
    const _Float16* __restrict__ H1, const _Float16* __restrict__ L1,
    const float* __restrict__ xn1, int* __restrict__ idx1, int k1)
{
    __shared__ float4 jbufH4[512];          // 8 KB  [chunk(8)][row(64)]
    __shared__ float4 jbufL4[512];          // 8 KB
    __shared__ unsigned ldsMV[4][64 * 11];  // 11 KB
    __shared__ unsigned short ldsMJ[4][64 * 11]; // 5.5 KB
    int raw = blockIdx.x;
    int bq = raw % 96;
    int q = raw / 96;
    int itile = q & 7, half = q >> 3;
    const _Float16* H = half ? H1 : H0;
    const _Float16* L = half ? L1 : L0;
    const float* xn = half ? xn1 : xn0;
    int* idx_out = half ? idx1 : idx0;
    int K = half ? k1 : k0;
    int tid = threadIdx.x, w = tid >> 6, l = tid & 63;
    int lane16 = l & 15, quad = l >> 4;
    const size_t base = (size_t)bq * 32768;
    const _Float16* Hb = H + base;
    const _Float16* Lb = L + base;
    // B operand = own i-row fragments (chunk layout)
    int ir = w * 16 + lane16;
    size_t bo = ((size_t)(itile * 8 + quad) * 64 + ir) * 8;
    half8 Bh0 = *(const half8*)(Hb + bo);
    half8 Bh1 = *(const half8*)(Hb + bo + 2048);
    half8 Bl0 = *(const half8*)(Lb + bo);
    half8 Bl1 = *(const half8*)(Lb + bo + 2048);

    unsigned kv[10]; int kj[10];           // ascending keys (kv[9] = best)
    #pragma unroll
    for (int qq = 0; qq < 10; ++qq) { kv[qq] = 0u; kj[qq] = 0; }

    auto casu = [](unsigned& a, unsigned& b) {
        unsigned mn = a < b ? a : b;
        unsigned mx = a < b ? b : a;
        a = mn; b = mx;
    };
    auto cas_kj = [](unsigned& ka, int& ja, unsigned& kb, int& jb2) {
        bool sw = ka > kb;
        unsigned tk = ka; int tj = ja;
        ka = sw ? kb : ka; ja = sw ? jb2 : ja;
        kb = sw ? tk : kb; jb2 = sw ? tj : jb2;
    };

    const float* xnb = xn + bq * 512;
    const _Float16* jH = (const _Float16*)jbufH4;
    const _Float16* jL = (const _Float16*)jbufL4;
    float4 pa0, pa1, pb0, pb1;
    {
        const float4* gh = (const float4*)(Hb);
        const float4* gl = (const float4*)(Lb);
        pa0 = gh[tid]; pa1 = gh[256 + tid];
        pb0 = gl[tid]; pb1 = gl[256 + tid];
    }
    for (int jt = 0; jt < 8; ++jt) {
        if (jt) __syncthreads();           // prev compute done reading jbuf
        jbufH4[tid] = pa0; jbufH4[256 + tid] = pa1;
        jbufL4[tid] = pb0; jbufL4[256 + tid] = pb1;
        __syncthreads();                   // tile staged
        if (jt < 7) {                      // prefetch next tile during compute
            const float4* gh = (const float4*)(Hb + (jt + 1) * 4096);
            const float4* gl = (const float4*)(Lb + (jt + 1) * 4096);
            pa0 = gh[tid]; pa1 = gh[256 + tid];
            pb0 = gl[tid]; pb1 = gl[256 + tid];
        }
        unsigned d[16];
        #pragma unroll
        for (int g = 0; g < 4; ++g) {
            int u = quad * 64 + g * 16 + lane16;   // chunk quad, row g*16+lane16
            half8 Ah0 = *(const half8*)(jH + (size_t)u * 8);
            half8 Ah1 = *(const half8*)(jH + (size_t)u * 8 + 2048);
            half8 Al0 = *(const half8*)(jL + (size_t)u * 8);
            half8 Al1 = *(const half8*)(jL + (size_t)u * 8 + 2048);
            f32x4 acc = {0.f, 0.f, 0.f, 0.f};
            acc = __builtin_amdgcn_mfma_f32_16x16x32_f16(Ah0, Bh0, acc, 0, 0, 0);
            acc = __builtin_amdgcn_mfma_f32_16x16x32_f16(Ah1, Bh1, acc, 0, 0, 0);
            acc = __builtin_amdgcn_mfma_f32_16x16x32_f16(Al0, Bh0, acc, 0, 0, 0);
            acc = __builtin_amdgcn_mfma_f32_16x16x32_f16(Al1, Bh1, acc, 0, 0, 0);
            acc = __builtin_amdgcn_mfma_f32_16x16x32_f16(Ah0, Bl0, acc, 0, 0, 0);
            acc = __builtin_amdgcn_mfma_f32_16x16x32_f16(Ah1, Bl1, acc, 0, 0, 0);
            int jb = jt * 64 + g * 16 + quad * 4;   // lane holds j = jb..jb+3
            float4 xn4 = *(const float4*)&xnb[jb];
            #pragma unroll
            for (int r = 0; r < 4; ++r) {
                float sc = 2.f * acc[r] - (r == 0 ? xn4.x : r == 1 ? xn4.y : r == 2 ? xn4.z : xn4.w);
                int bi = __float_as_int(sc);
                unsigned u2 = (unsigned)(bi ^ ((bi >> 31) | 0x80000000));
                int slot = g * 4 + r;               // j strictly increasing in slot
                d[slot] = (u2 & 0xFFFFFFF0u) | (unsigned)(15 - slot);
            }
        }
        // Batcher odd-even mergesort-16 ascending, value-only (2-inst CAS)
        #pragma unroll
        for (int p = 1; p < 16; p <<= 1) {
            #pragma unroll
            for (int k = p; k >= 1; k >>= 1) {
                #pragma unroll
                for (int j = k & (p - 1); j + k < 16; j += 2 * k) {
                    #pragma unroll
                    for (int i = 0; i < k; ++i) {
                        if ((i + j + k < 16) &&
                            ((i + j) / (2 * p) == (i + j + k) / (2 * p)))
                            casu(d[i + j], d[i + j + k]);
                    }
                }
            }
        }
        // top-10 of union: pair kv[i] (asc) with d[15-i], decode j for taken
        #pragma unroll
        for (int i = 0; i < 10; ++i) {
            unsigned dv = d[15 - i];
            int code = 15 - (int)(dv & 15u);
            int jnew = jt * 64 + (code >> 2) * 16 + quad * 4 + (code & 3);
            bool keep = kv[i] >= dv;
            kj[i] = keep ? kj[i] : jnew;
            kv[i] = keep ? kv[i] : dv;
        }
        // bitonic clean length-10
        cas_kj(kv[0], kj[0], kv[8], kj[8]);
        cas_kj(kv[1], kj[1], kv[9], kj[9]);
        cas_kj(kv[0], kj[0], kv[4], kj[4]);
        cas_kj(kv[1], kj[1], kv[5], kj[5]);
        cas_kj(kv[2], kj[2], kv[6], kj[6]);
        cas_kj(kv[3], kj[3], kv[7], kj[7]);
        cas_kj(kv[0], kj[0], kv[2], kj[2]);
        cas_kj(kv[1], kj[1], kv[3], kj[3]);
        cas_kj(kv[4], kj[4], kv[6], kj[6]);
        cas_kj(kv[5], kj[5], kv[7], kj[7]);
        cas_kj(kv[0], kj[0], kv[1], kj[1]);
        cas_kj(kv[2], kj[2], kv[3], kj[3]);
        cas_kj(kv[4], kj[4], kv[5], kj[5]);
        cas_kj(kv[6], kj[6], kv[7], kj[7]);
        cas_kj(kv[8], kj[8], kv[9], kj[9]);
    }
    // dump sorted-10 per quad, merge 4 lists per row (key desc, tie: smaller j)
    #pragma unroll
    for (int qq = 0; qq < 10; ++qq) {
        ldsMV[w][(lane16 * 4 + quad) * 11 + qq] = kv[qq];
        ldsMJ[w][(lane16 * 4 + quad) * 11 + qq] = (unsigned short)kj[qq];
    }
    __syncthreads();
    if (quad == 0) {
        const unsigned* MV = &ldsMV[w][lane16 * 44];
        const unsigned short* MJ = &ldsMJ[w][lane16 * 44];
        int p0 = 9, p1 = 9, p2 = 9, p3 = 9;
        int irow = itile * 64 + w * 16 + lane16;
        int* op = idx_out + ((size_t)bq * 512 + irow) * 16;
        for (int t = 0; t < K; ++t) {
            unsigned bv = 0u; int bj = 0x7fffffff; int bc = -1;
            { unsigned v = MV[p0]; int j = MJ[p0];
              if (v > bv || (v == bv && j < bj)) { bv = v; bj = j; bc = 0; } }
            { unsigned v = MV[11 + p1]; int j = MJ[11 + p1];
              if (v > bv || (v == bv && j < bj)) { bv = v; bj = j; bc = 1; } }
            { unsigned v = MV[22 + p2]; int j = MJ[22 + p2];
              if (v > bv || (v == bv && j < bj)) { bv = v; bj = j; bc = 2; } }
            { unsigned v = MV[33 + p3]; int j = MJ[33 + p3];
              if (v > bv || (v == bv && j < bj)) { bv = v; bj = j; bc = 3; } }
            if (bc == 0) --p0; else if (bc == 1) --p1; else if (bc == 2) --p2; else --p3;
            op[t] = bj;
        }
    }
}

// ---------------- fused branch v2: grid (96,4), 16 o's per block, 2 blocks/CU ----------------
template<int ACC>
__global__ __launch_bounds__(256) void fused_branch_kernel(
    const _Float16* __restrict__ H, const _Float16* __restrict__ L,
    const _Float16* __restrict__ WH, const _Float16* __restrict__ WL,
    const int* __restrict__ idx,
    const float* __restrict__ g, const float* __restrict__ bb,
    const float* __restrict__ mm, const float* __restrict__ vv,
    float* __restrict__ out_p, float* __restrict__ vec_out)
{
    __shared__ float ldsA[16 * 512];          // 32 KB: A rows ob..ob+15
    __shared__ float ldsB[16 * 512];          // 32 KB: B rows 64+ob..64+ob+15
    __shared__ unsigned short ldsIdx[512 * 10]; // 10 KB
    int bq = blockIdx.x, ob = blockIdx.y * 16;
    int tid = threadIdx.x, w = tid >> 6, l = tid & 63;
    int lane16 = l & 15, quad = l >> 4;
    const size_t base = (size_t)bq * 32768;
    for (int p = 0; p < 20; ++p) {
        int t = p * 256 + tid;
        int i = t / 10, q = t - i * 10;
        ldsIdx[t] = (unsigned short)idx[((size_t)bq * 512 + i) * 16 + q];
    }
    // phase 1: waves 0,2 -> A (itiles 0-15 / 16-31); waves 1,3 -> B
    {
        int part = w & 1;
        int it0 = (w >> 1) * 16;
        int wrow = (part ? 64 + ob : ob) + lane16;
        size_t woff = (size_t)wrow * 64 + quad * 8;
        half8 Ah0 = *(const half8*)(WH + woff);
        half8 Ah1 = *(const half8*)(WH + woff + 32);
        half8 Al0 = *(const half8*)(WL + woff);
        half8 Al1 = *(const half8*)(WL + woff + 32);
        float* dst = part ? ldsB : ldsA;
        for (int k = 0; k < 16; ++k) {
            int it = it0 + k;
            size_t off = base + (((size_t)(it >> 2) * 8 + quad) * 64 + (it & 3) * 16 + lane16) * 8;
            half8 Xh0 = *(const half8*)(H + off);
            half8 Xh1 = *(const half8*)(H + off + 2048);
            half8 Xl0 = *(const half8*)(L + off);
            half8 Xl1 = *(const half8*)(L + off + 2048);
            f32x4 acc = {0.f, 0.f, 0.f, 0.f};
            acc = __builtin_amdgcn_mfma_f32_16x16x32_f16(Ah0, Xh0, acc, 0, 0, 0);
            acc = __builtin_amdgcn_mfma_f32_16x16x32_f16(Ah1, Xh1, acc, 0, 0, 0);
            acc = __builtin_amdgcn_mfma_f32_16x16x32_f16(Ah0, Xl0, acc, 0, 0, 0);
            acc = __builtin_amdgcn_mfma_f32_16x16x32_f16(Ah1, Xl1, acc, 0, 0, 0);
            acc = __builtin_amdgcn_mfma_f32_16x16x32_f16(Al0, Xh0, acc, 0, 0, 0);
            acc = __builtin_amdgcn_mfma_f32_16x16x32_f16(Al1, Xh1, acc, 0, 0, 0);
            #pragma unroll
            for (int r = 0; r < 4; ++r)
                dst[(quad * 4 + r) * 512 + it * 16 + lane16] = acc[r];
        }
    }
    __syncthreads();
    // phase 2: wave w reduces o_local = w*4 + (0..3)
    float ssr[4], str[4];
    #pragma unroll
    for (int oo = 0; oo < 4; ++oo) {
        int o = ob + w * 4 + oo;
        float sc = g[o] / sqrtf(vv[o] + EPS);
        ssr[oo] = sc;
        str[oo] = bb[o] - mm[o] * sc;
    }
    float omax[4], osum[4];
    #pragma unroll
    for (int oo = 0; oo < 4; ++oo) { omax[oo] = -3.4e38f; osum[oo] = 0.f; }
    const float* Aw = ldsA + (w * 4) * 512;
    const float* Bw = ldsB + (w * 4) * 512;
    for (int s = 0; s < 8; ++s) {
        int i = l + 64 * s;
        int idr[10];
        const unsigned short* ip = &ldsIdx[i * 10];
        #pragma unroll
        for (int q = 0; q < 10; ++q) idr[q] = ip[q];
        #pragma unroll
        for (int oo = 0; oo < 4; ++oo) {
            const float* Ao = Aw + oo * 512;
            float mx = Ao[idr[0]];
            #pragma unroll
            for (int q = 1; q < 10; ++q) mx = fmaxf(mx, Ao[idr[q]]);
            float val = (mx + Bw[oo * 512 + i]) * ssr[oo] + str[oo];
            float y = val > 0.f ? val : 0.2f * val;
            omax[oo] = fmaxf(omax[oo], y);
            osum[oo] += y;
        }
    }
    #pragma unroll
    for (int oo = 0; oo < 4; ++oo) {
        float M = omax[oo], S = osum[oo];
        #pragma unroll
        for (int off = 32; off >= 1; off >>= 1) {
            M = fmaxf(M, __shfl_down(M, off));
            S += __shfl_down(S, off);
        }
        if (l == 0) {
            int o = ob + w * 4 + oo;
            float* po = out_p + bq * 128;
            if (ACC) {
                po[o] += M;
                po[64 + o] += S * (1.f / 512.f);
            } else {
                po[o] = M;
                po[64 + o] = S * (1.f / 512.f);
                vec_out[bq * 64 + o] = M;
            }
        }
    }
}

// ---------------- corre_binar: f, masks ----------------
__global__ __launch_bounds__(256) void corre_kernel(
    const float* __restrict__ x, const float* __restrict__ x0vec,
    const float* __restrict__ w_reduce, const int* __restrict__ idx8,
    float* __restrict__ fbuf, float* __restrict__ masks)
{
    __shared__ float sxv[64], sq[64], ss[512], sfk[512];
    int bq = blockIdx.x, tid = threadIdx.x;
    int row = src_row(bq);
    const float* Xb = x + (size_t)row * 32768;
    if (tid < 64) sxv[tid] = x0vec[bq * 64 + tid];
    __syncthreads();
    if (tid < 64) {
        float a = 0.f;
        for (int c = 0; c < 64; ++c) a += w_reduce[tid * 64 + c] * sxv[c];
        sq[tid] = a;
    }
    __syncthreads();
    for (int i = tid; i < 512; i += 256) {
        float a = 0.f;
        for (int c = 0; c < 64; ++c) a += sq[c] * Xb[c * 512 + i];
        a *= 0.125f;
        ss[i] = a;
        fbuf[bq * 512 + i] = a;
    }
    __syncthreads();
    for (int i = tid; i < 512; i += 256) {
        float a = ss[i];
        const int* ip = idx8 + ((size_t)bq * 512 + i) * 16;
        for (int q = 0; q < 8; ++q) a += ss[ip[q]];
        sfk[i] = a;
    }
    masks[bq * 512 + tid] = 1.0f;
    masks[bq * 512 + tid + 256] = 1.0f;
    __syncthreads();
    if (tid == 0) {
        float best = sfk[0]; int bi = 0;
        for (int i = 1; i < 512; ++i) if (sfk[i] > best) { best = sfk[i]; bi = i; }
        masks[bq * 512 + bi] = 0.f;
        const int* ip = idx8 + ((size_t)bq * 512 + bi) * 16;
        for (int q = 0; q < 8; ++q) masks[bq * 512 + ip[q]] = 0.f;
    }
}

// ---------------- erase1 fused with prep: x1e -> h/l split (chunk layout) + colnorms ----------------
__global__ __launch_bounds__(256) void erase1_kernel(
    const float* __restrict__ x, const float* __restrict__ masks,
    const float* __restrict__ fbuf,
    const float* __restrict__ w_e, const float* __restrict__ b_e,
    const float* __restrict__ g_e, const float* __restrict__ be_e,
    const float* __restrict__ m_e, const float* __restrict__ v_e,
    _Float16* __restrict__ H, _Float16* __restrict__ L, float* __restrict__ xn)
{
    __shared__ float sw[512];
    __shared__ float smk[512];
    __shared__ float red[256];
    __shared__ float sres[64];
    __shared__ float sy[64];
    __shared__ float lds[64 * 65];
    __shared__ float xnp[4 * 64];
    int bq = blockIdx.x, tid = threadIdx.x;
    int row = src_row(bq);
    const float* Xb = x + (size_t)row * 32768;
    float f0 = fbuf[bq * 512 + tid], f1 = fbuf[bq * 512 + tid + 256];
    float mk0 = masks[bq * 512 + tid], mk1 = masks[bq * 512 + tid + 256];
    smk[tid] = mk0; smk[tid + 256] = mk1;
    float s0 = f0 - (1.f - mk0) * 1e8f, s1 = f1 - (1.f - mk1) * 1e8f;
    red[tid] = fmaxf(s0, s1);
    __syncthreads();
    for (int off = 128; off >= 1; off >>= 1) {
        if (tid < off) red[tid] = fmaxf(red[tid], red[tid + off]);
        __syncthreads();
    }
    float mx = red[0];
    __syncthreads();
    float e0 = expf(s0 - mx), e1 = expf(s1 - mx);
    red[tid] = e0 + e1;
    __syncthreads();
    for (int off = 128; off >= 1; off >>= 1) {
        if (tid < off) red[tid] = red[tid] + red[tid + off];
        __syncthreads();
    }
    float inv = 1.f / red[0];
    __syncthreads();
    sw[tid] = e0 * inv; sw[tid + 256] = e1 * inv;
    __syncthreads();
    int c4 = tid >> 2, p4 = tid & 3;
    {
        float a = 0.f;
        const float* xr = Xb + c4 * 512 + p4 * 128;
        const float* wr = &sw[p4 * 128];
        for (int ii = 0; ii < 128; ++ii) a += xr[ii] * wr[ii];
        red[tid] = a;
    }
    __syncthreads();
    if (p4 == 0) sres[c4] = red[tid] + red[tid + 1] + red[tid + 2] + red[tid + 3];
    __syncthreads();
    if (tid < 64) {
        float a = b_e[tid];
        for (int cc = 0; cc < 64; ++cc) a += w_e[tid * 64 + cc] * sres[cc];
        float sc = g_e[tid] / sqrtf(v_e[tid] + EPS);
        sy[tid] = (a - m_e[tid]) * sc + be_e[tid];
    }
    for (int tt = 0; tt < 8; ++tt) {
        __syncthreads();
        for (int p = 0; p < 16; ++p) {
            int t = p * 256 + tid;
            int c = t >> 6, col = t & 63;
            float v = Xb[c * 512 + tt * 64 + col] * smk[tt * 64 + col] + sy[c];
            lds[c * 65 + col] = v;
        }
        __syncthreads();
        int col = tid & 63, g = tid >> 6;
        half8 hv[2], lv[2];
        float s = 0.f;
        #pragma unroll
        for (int k = 0; k < 16; ++k) {
            int c = g * 16 + k;
            float v = lds[c * 65 + col];
            _Float16 h = (_Float16)v;
            _Float16 lo = (_Float16)(v - (float)h);
            hv[k >> 3][k & 7] = h;
            lv[k >> 3][k & 7] = lo;
            s += v * v;
        }
        size_t obase = (size_t)bq * 32768 + ((size_t)(tt * 8 + 2 * g) * 64 + col) * 8;
        *(half8*)(H + obase) = hv[0];
        *(half8*)(H + obase + 512) = hv[1];
        *(half8*)(L + obase) = lv[0];
        *(half8*)(L + obase + 512) = lv[1];
        xnp[g * 64 + col] = s;
        __syncthreads();
        if (tid < 64)
            xn[bq * 512 + tt * 64 + tid] =
                xnp[tid] + xnp[64 + tid] + xnp[128 + tid] + xnp[192 + tid];
    }
}

extern "C" void kernel_launch(void* const* d_in, const int* in_sizes, int n_in,
                              void* d_out, int out_size, void* d_ws, size_t ws_size,
                              hipStream_t stream)
{
    const float* x        = (const float*)d_in[0];
    const float* w_reduce = (const float*)d_in[1];
    const float* w_erase  = (const float*)d_in[2];
    const float* b_erase  = (const float*)d_in[3];
    const float* g_erase  = (const float*)d_in[4];
    const float* be_erase = (const float*)d_in[5];
    const float* m_erase  = (const float*)d_in[6];
    const float* v_erase  = (const float*)d_in[7];
    const float* w0 = (const float*)d_in[8];
    const float* g0 = (const float*)d_in[9];
    const float* b0 = (const float*)d_in[10];
    const float* m0 = (const float*)d_in[11];
    const float* v0 = (const float*)d_in[12];
    const float* w1 = (const float*)d_in[13];
    const float* g1 = (const float*)d_in[14];
    const float* b1 = (const float*)d_in[15];
    const float* m1 = (const float*)d_in[16];
    const float* v1 = (const float*)d_in[17];
    float* out = (float*)d_out;
    char* ws = (char*)d_ws;

    _Float16* h0 = (_Float16*)(ws);              // 6.29 MB  x0 / x1e
    _Float16* l0 = (_Float16*)(ws + 6291456);    // 6.29 MB
    _Float16* h1 = (_Float16*)(ws + 12582912);   // 6.29 MB  x1seq
    _Float16* l1 = (_Float16*)(ws + 18874368);   // 6.29 MB
    int*   idxA  = (int*)(ws + 37748736);        // 3.15 MB
    int*   idx8  = (int*)(ws + 40894464);        // 3.15 MB
    float* xn0   = (float*)(ws + 44040192);      // 192 KB
    float* xn1   = (float*)(ws + 44236800);      // 192 KB
    float* y0vec = (float*)(ws + 44433408);      // 24 KB
    float* x0vec = (float*)(ws + 44457984);      // 24 KB
    float* fbuf  = (float*)(ws + 44482560);      // 192 KB
    float* masks = (float*)(ws + 44679168);      // 192 KB
    _Float16* wh0 = (_Float16*)(ws + 44875776);  // 16 KB
    _Float16* wl0 = (_Float16*)(ws + 44892160);  // 16 KB
    _Float16* wh1 = (_Float16*)(ws + 44908544);  // 16 KB
    _Float16* wl1 = (_Float16*)(ws + 44924928);  // 16 KB

    (void)in_sizes; (void)n_in; (void)out_size; (void)ws_size;

    erase0_kernel<<<96, 256, 0, stream>>>(x, w_erase, b_erase, g_erase, be_erase, m_erase, v_erase, y0vec);
    prep_kernel<<<1536, 256, 0, stream>>>(x, y0vec, h0, l0, xn0, h1, l1, xn1,
                                          w0, w1, wh0, wl0, wh1, wl1);
    knn_kernel<<<1536, 256, 0, stream>>>(h0, l0, xn0, idxA, 10, h1, l1, xn1, idx8, 8);
    fused_branch_kernel<0><<<dim3(96, 4), 256, 0, stream>>>(h0, l0, wh0, wl0, idxA,
                                                            g0, b0, m0, v0, out, x0vec);
    corre_kernel<<<96, 256, 0, stream>>>(x, x0vec, w_reduce, idx8, fbuf, masks);
    erase1_kernel<<<96, 256, 0, stream>>>(x, masks, fbuf, w_erase, b_erase, g_erase, be_erase, m_erase, v_erase,
                                          h0, l0, xn0);
    knn_kernel<<<768, 256, 0, stream>>>(h0, l0, xn0, idxA, 10, h0, l0, xn0, idxA, 10);
    fused_branch_kernel<1><<<dim3(96, 4), 256, 0, stream>>>(h0, l0, wh1, wl1, idxA,
                                                            g1, b1, m1, v1, out, nullptr);
}

// Round 10
// 308.393 us; speedup vs baseline: 1.3644x; 1.0283x over previous
//
#include <hip/hip_runtime.h>
#include <math.h>

#define EPS 1e-5f

typedef _Float16 half8 __attribute__((ext_vector_type(8)));
typedef float f32x4 __attribute__((ext_vector_type(4)));

// H/L global layout per row: [tile(8)][chunk(8)][col(64)] x 8 halves (16B units).

// bq in [0,96): b = bq/12, t = bq%12; x1seq row = b*12 + min(t+1, 11)
__device__ __forceinline__ int src_row(int bq) {
    int b = bq / 12, t = bq - b * 12;
    int t2 = (t + 1 < 12) ? (t + 1) : 11;
    return b * 12 + t2;
}

// ---------------- erase0: y0 = BN(W_e @ mean_n(x) + b_e); bias0 = W2_0 @ y0 ----------------
__global__ __launch_bounds__(256) void erase0_kernel(
    const float* __restrict__ x, const float* __restrict__ w0,
    const float* __restrict__ w_e, const float* __restrict__ b_e,
    const float* __restrict__ g_e, const float* __restrict__ be_e,
    const float* __restrict__ m_e, const float* __restrict__ v_e,
    float* __restrict__ bias0)
{
    __shared__ float part[256];
    __shared__ float res[64];
    __shared__ float sy[64];
    int bq = blockIdx.x, tid = threadIdx.x;
    int c = tid >> 2, p = tid & 3;
    const float* xb = x + (size_t)bq * 32768 + c * 512 + p * 128;
    float acc = 0.f;
    for (int ii = 0; ii < 128; ii += 4) {
        float4 v = *(const float4*)(xb + ii);
        acc += v.x + v.y + v.z + v.w;
    }
    part[tid] = acc;
    __syncthreads();
    if (p == 0) res[c] = (part[tid] + part[tid+1] + part[tid+2] + part[tid+3]) * (1.f/512.f);
    __syncthreads();
    if (tid < 64) {
        float a = b_e[tid];
        for (int cc = 0; cc < 64; ++cc) a += w_e[tid*64+cc] * res[cc];
        float s = g_e[tid] / sqrtf(v_e[tid] + EPS);
        sy[tid] = (a - m_e[tid]) * s + be_e[tid];
    }
    __syncthreads();
    if (tid < 64) {
        float a = 0.f;
        for (int cc = 0; cc < 64; ++cc) a += w0[tid * 128 + 64 + cc] * sy[cc];
        bias0[bq * 64 + tid] = a;
    }
}

// ---------------- prep: fp16 split of raw x (chunk layout) + colnorms + W' splits ----------------
// grid = 768. blockIdx = ct*96 + bq (XCD swizzle).
__global__ __launch_bounds__(256) void prep_kernel(
    const float* __restrict__ X,
    _Float16* __restrict__ H, _Float16* __restrict__ L, float* __restrict__ xn,
    const float* __restrict__ w0, const float* __restrict__ w1,
    _Float16* __restrict__ wh0, _Float16* __restrict__ wl0,
    _Float16* __restrict__ wh1, _Float16* __restrict__ wl1)
{
    __shared__ float lds[64 * 65];
    __shared__ float xnp[4 * 64];
    int raw = blockIdx.x;
    int bq = raw % 96;
    int ct = raw / 96;
    const float* Xb = X + (size_t)bq * 32768 + ct * 64;
    int tid = threadIdx.x;
    for (int p = 0; p < 16; ++p) {
        int t = p * 256 + tid;
        int c = t >> 6, col = t & 63;
        lds[c * 65 + col] = Xb[c * 512 + col];
    }
    __syncthreads();
    int col = tid & 63, g = tid >> 6;
    half8 hv[2], lv[2];
    float s = 0.f;
    #pragma unroll
    for (int k = 0; k < 16; ++k) {
        int c = g * 16 + k;
        float v = lds[c * 65 + col];
        _Float16 h = (_Float16)v;
        _Float16 lo = (_Float16)(v - (float)h);
        hv[k >> 3][k & 7] = h;
        lv[k >> 3][k & 7] = lo;
        s += v * v;
    }
    size_t obase = (size_t)bq * 32768 + ((size_t)(ct * 8 + 2 * g) * 64 + col) * 8;
    *(half8*)(H + obase) = hv[0];
    *(half8*)(H + obase + 512) = hv[1];
    *(half8*)(L + obase) = lv[0];
    *(half8*)(L + obase + 512) = lv[1];
    xnp[g * 64 + col] = s;
    __syncthreads();
    if (tid < 64)
        xn[bq * 512 + ct * 64 + tid] =
            xnp[tid] + xnp[64 + tid] + xnp[128 + tid] + xnp[192 + tid];
    if (raw < 2) {
        const float* W = raw ? w1 : w0;
        _Float16* WH = raw ? wh1 : wh0;
        _Float16* WL = raw ? wl1 : wl0;
        for (int t = tid; t < 8192; t += 256) {
            int o = t >> 6, c = t & 63;
            float v = (o < 64) ? W[o * 128 + c]
                               : (W[(o - 64) * 128 + 64 + c] - W[(o - 64) * 128 + c]);
            _Float16 h = (_Float16)v;
            WH[t] = h;
            WL[t] = (_Float16)(v - (float)h);
        }
    }
}

// ---------------- kNN: LDS-staged tiles + MFMA + value-only sort; optional mask+remap ----------------
// masks!=null: cloud = row src_row(bq) with masked columns zeroed (x1e translation-reduced).
__global__ __launch_bounds__(256, 5) void knn_kernel(
    const _Float16* __restrict__ H, const _Float16* __restrict__ L,
    const float* __restrict__ xn, const float* __restrict__ masks, int remap,
    int* __restrict__ idx_out, int K)
{
    __shared__ float4 jbufH4[512];
    __shared__ float4 jbufL4[512];
    __shared__ float smask[512];
    __shared__ unsigned ldsMV[4][64 * 11];
    __shared__ unsigned short ldsMJ[4][64 * 11];
    int raw = blockIdx.x;
    int bq = raw % 96;
    int itile = raw / 96;
    int row = remap ? src_row(bq) : bq;
    bool use_mask = (masks != nullptr);
    int tid = threadIdx.x, w = tid >> 6, l = tid & 63;
    int lane16 = l & 15, quad = l >> 4;
    const size_t base = (size_t)row * 32768;
    const _Float16* Hb = H + base;
    const _Float16* Lb = L + base;
    if (use_mask) {
        smask[tid] = masks[bq * 512 + tid];
        smask[tid + 256] = masks[bq * 512 + tid + 256];
    }
    int irow = itile * 64 + w * 16 + lane16;
    size_t bo = ((size_t)(itile * 8 + quad) * 64 + irow - (size_t)itile * 64) * 8 + (size_t)itile * 64 * 64 * 0;
    bo = ((size_t)(itile * 8 + quad) * 64 + (w * 16 + lane16)) * 8;
    half8 Bh0 = *(const half8*)(Hb + bo);
    half8 Bh1 = *(const half8*)(Hb + bo + 2048);
    half8 Bl0 = *(const half8*)(Lb + bo);
    half8 Bl1 = *(const half8*)(Lb + bo + 2048);
    if (use_mask) {
        float bm = masks[bq * 512 + irow];
        if (bm == 0.f) {
            half8 z = {};
            Bh0 = z; Bh1 = z; Bl0 = z; Bl1 = z;
        }
    }

    unsigned kv[10]; int kj[10];
    #pragma unroll
    for (int qq = 0; qq < 10; ++qq) { kv[qq] = 0u; kj[qq] = 0; }

    auto casu = [](unsigned& a, unsigned& b) {
        unsigned mn = a < b ? a : b;
        unsigned mx = a < b ? b : a;
        a = mn; b = mx;
    };
    auto cas_kj = [](unsigned& ka, int& ja, unsigned& kb, int& jb2) {
        bool sw = ka > kb;
        unsigned tk = ka; int tj = ja;
        ka = sw ? kb : ka; ja = sw ? jb2 : ja;
        kb = sw ? tk : kb; jb2 = sw ? tj : jb2;
    };

    const float* xnb = xn + row * 512;
    const _Float16* jH = (const _Float16*)jbufH4;
    const _Float16* jL = (const _Float16*)jbufL4;
    float4 pa0, pa1, pb0, pb1;
    {
        const float4* gh = (const float4*)(Hb);
        const float4* gl = (const float4*)(Lb);
        pa0 = gh[tid]; pa1 = gh[256 + tid];
        pb0 = gl[tid]; pb1 = gl[256 + tid];
    }
    __syncthreads();                        // smask visible before first masked stage
    for (int jt = 0; jt < 8; ++jt) {
        if (jt) __syncthreads();
        if (use_mask) {
            float m = smask[jt * 64 + (tid & 63)];
            float4 z4 = {0.f, 0.f, 0.f, 0.f};
            bool on = (m != 0.f);
            jbufH4[tid] = on ? pa0 : z4; jbufH4[256 + tid] = on ? pa1 : z4;
            jbufL4[tid] = on ? pb0 : z4; jbufL4[256 + tid] = on ? pb1 : z4;
        } else {
            jbufH4[tid] = pa0; jbufH4[256 + tid] = pa1;
            jbufL4[tid] = pb0; jbufL4[256 + tid] = pb1;
        }
        __syncthreads();
        if (jt < 7) {
            const float4* gh = (const float4*)(Hb + (jt + 1) * 4096);
            const float4* gl = (const float4*)(Lb + (jt + 1) * 4096);
            pa0 = gh[tid]; pa1 = gh[256 + tid];
            pb0 = gl[tid]; pb1 = gl[256 + tid];
        }
        unsigned d[16];
        #pragma unroll
        for (int g = 0; g < 4; ++g) {
            int u = quad * 64 + g * 16 + lane16;
            half8 Ah0 = *(const half8*)(jH + (size_t)u * 8);
            half8 Ah1 = *(const half8*)(jH + (size_t)u * 8 + 2048);
            half8 Al0 = *(const half8*)(jL + (size_t)u * 8);
            half8 Al1 = *(const half8*)(jL + (size_t)u * 8 + 2048);
            f32x4 acc = {0.f, 0.f, 0.f, 0.f};
            acc = __builtin_amdgcn_mfma_f32_16x16x32_f16(Ah0, Bh0, acc, 0, 0, 0);
            acc = __builtin_amdgcn_mfma_f32_16x16x32_f16(Ah1, Bh1, acc, 0, 0, 0);
            acc = __builtin_amdgcn_mfma_f32_16x16x32_f16(Al0, Bh0, acc, 0, 0, 0);
            acc = __builtin_amdgcn_mfma_f32_16x16x32_f16(Al1, Bh1, acc, 0, 0, 0);
            acc = __builtin_amdgcn_mfma_f32_16x16x32_f16(Ah0, Bl0, acc, 0, 0, 0);
            acc = __builtin_amdgcn_mfma_f32_16x16x32_f16(Ah1, Bl1, acc, 0, 0, 0);
            int jb = jt * 64 + g * 16 + quad * 4;
            float4 xn4 = *(const float4*)&xnb[jb];
            if (use_mask) {
                float4 sm4 = *(const float4*)&smask[jb];
                if (sm4.x == 0.f) xn4.x = 0.f;
                if (sm4.y == 0.f) xn4.y = 0.f;
                if (sm4.z == 0.f) xn4.z = 0.f;
                if (sm4.w == 0.f) xn4.w = 0.f;
            }
            #pragma unroll
            for (int r = 0; r < 4; ++r) {
                float sc = 2.f * acc[r] - (r == 0 ? xn4.x : r == 1 ? xn4.y : r == 2 ? xn4.z : xn4.w);
                int bi = __float_as_int(sc);
                unsigned u2 = (unsigned)(bi ^ ((bi >> 31) | 0x80000000));
                int slot = g * 4 + r;
                d[slot] = (u2 & 0xFFFFFFF0u) | (unsigned)(15 - slot);
            }
        }
        #pragma unroll
        for (int p = 1; p < 16; p <<= 1) {
            #pragma unroll
            for (int k = p; k >= 1; k >>= 1) {
                #pragma unroll
                for (int j = k & (p - 1); j + k < 16; j += 2 * k) {
                    #pragma unroll
                    for (int i = 0; i < k; ++i) {
                        if ((i + j + k < 16) &&
                            ((i + j) / (2 * p) == (i + j + k) / (2 * p)))
                            casu(d[i + j], d[i + j + k]);
                    }
                }
            }
        }
        #pragma unroll
        for (int i = 0; i < 10; ++i) {
            unsigned dv = d[15 - i];
            int code = 15 - (int)(dv & 15u);
            int jnew = jt * 64 + (code >> 2) * 16 + quad * 4 + (code & 3);
            bool keep = kv[i] >= dv;
            kj[i] = keep ? kj[i] : jnew;
            kv[i] = keep ? kv[i] : dv;
        }
        cas_kj(kv[0], kj[0], kv[8], kj[8]);
        cas_kj(kv[1], kj[1], kv[9], kj[9]);
        cas_kj(kv[0], kj[0], kv[4], kj[4]);
        cas_kj(kv[1], kj[1], kv[5], kj[5]);
        cas_kj(kv[2], kj[2], kv[6], kj[6]);
        cas_kj(kv[3], kj[3], kv[7], kj[7]);
        cas_kj(kv[0], kj[0], kv[2], kj[2]);
        cas_kj(kv[1], kj[1], kv[3], kj[3]);
        cas_kj(kv[4], kj[4], kv[6], kj[6]);
        cas_kj(kv[5], kj[5], kv[7], kj[7]);
        cas_kj(kv[0], kj[0], kv[1], kj[1]);
        cas_kj(kv[2], kj[2], kv[3], kj[3]);
        cas_kj(kv[4], kj[4], kv[5], kj[5]);
        cas_kj(kv[6], kj[6], kv[7], kj[7]);
        cas_kj(kv[8], kj[8], kv[9], kj[9]);
    }
    #pragma unroll
    for (int qq = 0; qq < 10; ++qq) {
        ldsMV[w][(lane16 * 4 + quad) * 11 + qq] = kv[qq];
        ldsMJ[w][(lane16 * 4 + quad) * 11 + qq] = (unsigned short)kj[qq];
    }
    __syncthreads();
    if (quad == 0) {
        const unsigned* MV = &ldsMV[w][lane16 * 44];
        const unsigned short* MJ = &ldsMJ[w][lane16 * 44];
        int p0 = 9, p1 = 9, p2 = 9, p3 = 9;
        int* op = idx_out + ((size_t)bq * 512 + irow) * 16;
        for (int t = 0; t < K; ++t) {
            unsigned bv = 0u; int bj = 0x7fffffff; int bc = -1;
            { unsigned v = MV[p0]; int j = MJ[p0];
              if (v > bv || (v == bv && j < bj)) { bv = v; bj = j; bc = 0; } }
            { unsigned v = MV[11 + p1]; int j = MJ[11 + p1];
              if (v > bv || (v == bv && j < bj)) { bv = v; bj = j; bc = 1; } }
            { unsigned v = MV[22 + p2]; int j = MJ[22 + p2];
              if (v > bv || (v == bv && j < bj)) { bv = v; bj = j; bc = 2; } }
            { unsigned v = MV[33 + p3]; int j = MJ[33 + p3];
              if (v > bv || (v == bv && j < bj)) { bv = v; bj = j; bc = 3; } }
            if (bc == 0) --p0; else if (bc == 1) --p1; else if (bc == 2) --p2; else --p3;
            op[t] = bj;
        }
    }
}

// ---------------- fused branch: grid (96,4); optional mask+remap; per-(bq,o) bias ----------------
template<int ACC>
__global__ __launch_bounds__(256) void fused_branch_kernel(
    const _Float16* __restrict__ H, const _Float16* __restrict__ L,
    const _Float16* __restrict__ WH, const _Float16* __restrict__ WL,
    const int* __restrict__ idx, const float* __restrict__ masks, int remap,
    const float* __restrict__ bias,
    const float* __restrict__ g, const float* __restrict__ bb,
    const float* __restrict__ mm, const float* __restrict__ vv,
    float* __restrict__ out_p, float* __restrict__ vec_out)
{
    __shared__ float ldsA[16 * 512];
    __shared__ float ldsB[16 * 512];
    __shared__ unsigned short ldsIdx[512 * 10];
    __shared__ float smask[512];
    int bq = blockIdx.x, ob = blockIdx.y * 16;
    int row = remap ? src_row(bq) : bq;
    bool use_mask = (masks != nullptr);
    int tid = threadIdx.x, w = tid >> 6, l = tid & 63;
    int lane16 = l & 15, quad = l >> 4;
    const size_t base = (size_t)row * 32768;
    for (int p = 0; p < 20; ++p) {
        int t = p * 256 + tid;
        int i = t / 10, q = t - i * 10;
        ldsIdx[t] = (unsigned short)idx[((size_t)bq * 512 + i) * 16 + q];
    }
    if (use_mask) {
        smask[tid] = masks[bq * 512 + tid];
        smask[tid + 256] = masks[bq * 512 + tid + 256];
    }
    __syncthreads();
    {
        int part = w & 1;
        int it0 = (w >> 1) * 16;
        int wrow = (part ? 64 + ob : ob) + lane16;
        size_t woff = (size_t)wrow * 64 + quad * 8;
        half8 Ah0 = *(const half8*)(WH + woff);
        half8 Ah1 = *(const half8*)(WH + woff + 32);
        half8 Al0 = *(const half8*)(WL + woff);
        half8 Al1 = *(const half8*)(WL + woff + 32);
        float* dst = part ? ldsB : ldsA;
        for (int k = 0; k < 16; ++k) {
            int it = it0 + k;
            size_t off = base + (((size_t)(it >> 2) * 8 + quad) * 64 + (it & 3) * 16 + lane16) * 8;
            half8 Xh0 = *(const half8*)(H + off);
            half8 Xh1 = *(const half8*)(H + off + 2048);
            half8 Xl0 = *(const half8*)(L + off);
            half8 Xl1 = *(const half8*)(L + off + 2048);
            if (use_mask) {
                float m = smask[it * 16 + lane16];
                if (m == 0.f) {
                    half8 z = {};
                    Xh0 = z; Xh1 = z; Xl0 = z; Xl1 = z;
                }
            }
            f32x4 acc = {0.f, 0.f, 0.f, 0.f};
            acc = __builtin_amdgcn_mfma_f32_16x16x32_f16(Ah0, Xh0, acc, 0, 0, 0);
            acc = __builtin_amdgcn_mfma_f32_16x16x32_f16(Ah1, Xh1, acc, 0, 0, 0);
            acc = __builtin_amdgcn_mfma_f32_16x16x32_f16(Ah0, Xl0, acc, 0, 0, 0);
            acc = __builtin_amdgcn_mfma_f32_16x16x32_f16(Ah1, Xl1, acc, 0, 0, 0);
            acc = __builtin_amdgcn_mfma_f32_16x16x32_f16(Al0, Xh0, acc, 0, 0, 0);
            acc = __builtin_amdgcn_mfma_f32_16x16x32_f16(Al1, Xh1, acc, 0, 0, 0);
            #pragma unroll
            for (int r = 0; r < 4; ++r)
                dst[(quad * 4 + r) * 512 + it * 16 + lane16] = acc[r];
        }
    }
    __syncthreads();
    float ssr[4], str[4];
    #pragma unroll
    for (int oo = 0; oo < 4; ++oo) {
        int o = ob + w * 4 + oo;
        float sc = g[o] / sqrtf(vv[o] + EPS);
        ssr[oo] = sc;
        str[oo] = bb[o] - mm[o] * sc + bias[bq * 64 + o] * sc;
    }
    float omax[4], osum[4];
    #pragma unroll
    for (int oo = 0; oo < 4; ++oo) { omax[oo] = -3.4e38f; osum[oo] = 0.f; }
    const float* Aw = ldsA + (w * 4) * 512;
    const float* Bw = ldsB + (w * 4) * 512;
    for (int s = 0; s < 8; ++s) {
        int i = l + 64 * s;
        int idr[10];
        const unsigned short* ip = &ldsIdx[i * 10];
        #pragma unroll
        for (int q = 0; q < 10; ++q) idr[q] = ip[q];
        #pragma unroll
        for (int oo = 0; oo < 4; ++oo) {
            const float* Ao = Aw + oo * 512;
            float mx = Ao[idr[0]];
            #pragma unroll
            for (int q = 1; q < 10; ++q) mx = fmaxf(mx, Ao[idr[q]]);
            float val = (mx + Bw[oo * 512 + i]) * ssr[oo] + str[oo];
            float y = val > 0.f ? val : 0.2f * val;
            omax[oo] = fmaxf(omax[oo], y);
            osum[oo] += y;
        }
    }
    #pragma unroll
    for (int oo = 0; oo < 4; ++oo) {
        float M = omax[oo], S = osum[oo];
        #pragma unroll
        for (int off = 32; off >= 1; off >>= 1) {
            M = fmaxf(M, __shfl_down(M, off));
            S += __shfl_down(S, off);
        }
        if (l == 0) {
            int o = ob + w * 4 + oo;
            float* po = out_p + bq * 128;
            if (ACC) {
                po[o] += M;
                po[64 + o] += S * (1.f / 512.f);
            } else {
                po[o] = M;
                po[64 + o] = S * (1.f / 512.f);
                vec_out[bq * 64 + o] = M;
            }
        }
    }
}

// ---------------- corre_binar: f, masks (idx8 = prefix-8 of idxA[src_row(bq)]) ----------------
__global__ __launch_bounds__(256) void corre_kernel(
    const float* __restrict__ x, const float* __restrict__ x0vec,
    const float* __restrict__ w_reduce, const int* __restrict__ idxA,
    float* __restrict__ fbuf, float* __restrict__ masks)
{
    __shared__ float sxv[64], sq[64], ss[512], sfk[512];
    int bq = blockIdx.x, tid = threadIdx.x;
    int row = src_row(bq);
    const float* Xb = x + (size_t)row * 32768;
    if (tid < 64) sxv[tid] = x0vec[bq * 64 + tid];
    __syncthreads();
    if (tid < 64) {
        float a = 0.f;
        for (int c = 0; c < 64; ++c) a += w_reduce[tid * 64 + c] * sxv[c];
        sq[tid] = a;
    }
    __syncthreads();
    for (int i = tid; i < 512; i += 256) {
        float a = 0.f;
        for (int c = 0; c < 64; ++c) a += sq[c] * Xb[c * 512 + i];
        a *= 0.125f;
        ss[i] = a;
        fbuf[bq * 512 + i] = a;
    }
    __syncthreads();
    for (int i = tid; i < 512; i += 256) {
        float a = ss[i];
        const int* ip = idxA + ((size_t)row * 512 + i) * 16;
        for (int q = 0; q < 8; ++q) a += ss[ip[q]];
        sfk[i] = a;
    }
    masks[bq * 512 + tid] = 1.0f;
    masks[bq * 512 + tid + 256] = 1.0f;
    __syncthreads();
    if (tid == 0) {
        float best = sfk[0]; int bi = 0;
        for (int i = 1; i < 512; ++i) if (sfk[i] > best) { best = sfk[i]; bi = i; }
        masks[bq * 512 + bi] = 0.f;
        const int* ip = idxA + ((size_t)row * 512 + bi) * 16;
        for (int q = 0; q < 8; ++q) masks[bq * 512 + ip[q]] = 0.f;
    }
}

// ---------------- erase1 slim: y1 = BN(W_e @ softmax-pooled + b_e); bias1 = W2_1 @ y1 ----------------
__global__ __launch_bounds__(256) void erase1_kernel(
    const float* __restrict__ x, const float* __restrict__ masks,
    const float* __restrict__ fbuf,
    const float* __restrict__ w_e, const float* __restrict__ b_e,
    const float* __restrict__ g_e, const float* __restrict__ be_e,
    const float* __restrict__ m_e, const float* __restrict__ v_e,
    const float* __restrict__ w1, float* __restrict__ bias1)
{
    __shared__ float sw[512];
    __shared__ float red[256];
    __shared__ float sres[64];
    __shared__ float sy[64];
    int bq = blockIdx.x, tid = threadIdx.x;
    int row = src_row(bq);
    const float* Xb = x + (size_t)row * 32768;
    float f0 = fbuf[bq * 512 + tid], f1 = fbuf[bq * 512 + tid + 256];
    float mk0 = masks[bq * 512 + tid], mk1 = masks[bq * 512 + tid + 256];
    float s0 = f0 - (1.f - mk0) * 1e8f, s1 = f1 - (1.f - mk1) * 1e8f;
    red[tid] = fmaxf(s0, s1);
    __syncthreads();
    for (int off = 128; off >= 1; off >>= 1) {
        if (tid < off) red[tid] = fmaxf(red[tid], red[tid + off]);
        __syncthreads();
    }
    float mx = red[0];
    __syncthreads();
    float e0 = expf(s0 - mx), e1 = expf(s1 - mx);
    red[tid] = e0 + e1;
    __syncthreads();
    for (int off = 128; off >= 1; off >>= 1) {
        if (tid < off) red[tid] = red[tid] + red[tid + off];
        __syncthreads();
    }
    float inv = 1.f / red[0];
    __syncthreads();
    sw[tid] = e0 * inv; sw[tid + 256] = e1 * inv;
    __syncthreads();
    int c4 = tid >> 2, p4 = tid & 3;
    {
        float a = 0.f;
        const float* xr = Xb + c4 * 512 + p4 * 128;
        const float* wr = &sw[p4 * 128];
        for (int ii = 0; ii < 128; ++ii) a += xr[ii] * wr[ii];
        red[tid] = a;
    }
    __syncthreads();
    if (p4 == 0) sres[c4] = red[tid] + red[tid + 1] + red[tid + 2] + red[tid + 3];
    __syncthreads();
    if (tid < 64) {
        float a = b_e[tid];
        for (int cc = 0; cc < 64; ++cc) a += w_e[tid * 64 + cc] * sres[cc];
        float sc = g_e[tid] / sqrtf(v_e[tid] + EPS);
        sy[tid] = (a - m_e[tid]) * sc + be_e[tid];
    }
    __syncthreads();
    if (tid < 64) {
        float a = 0.f;
        for (int cc = 0; cc < 64; ++cc) a += w1[tid * 128 + 64 + cc] * sy[cc];
        bias1[bq * 64 + tid] = a;
    }
}

extern "C" void kernel_launch(void* const* d_in, const int* in_sizes, int n_in,
                              void* d_out, int out_size, void* d_ws, size_t ws_size,
                              hipStream_t stream)
{
    const float* x        = (const float*)d_in[0];
    const float* w_reduce = (const float*)d_in[1];
    const float* w_erase  = (const float*)d_in[2];
    const float* b_erase  = (const float*)d_in[3];
    const float* g_erase  = (const float*)d_in[4];
    const float* be_erase = (const float*)d_in[5];
    const float* m_erase  = (const float*)d_in[6];
    const float* v_erase  = (const float*)d_in[7];
    const float* w0 = (const float*)d_in[8];
    const float* g0 = (const float*)d_in[9];
    const float* b0 = (const float*)d_in[10];
    const float* m0 = (const float*)d_in[11];
    const float* v0 = (const float*)d_in[12];
    const float* w1 = (const float*)d_in[13];
    const float* g1 = (const float*)d_in[14];
    const float* b1 = (const float*)d_in[15];
    const float* m1 = (const float*)d_in[16];
    const float* v1 = (const float*)d_in[17];
    float* out = (float*)d_out;
    char* ws = (char*)d_ws;

    _Float16* h0 = (_Float16*)(ws);              // 6.29 MB  split of raw x
    _Float16* l0 = (_Float16*)(ws + 6291456);    // 6.29 MB
    int*   idxA  = (int*)(ws + 12582912);        // 3.15 MB
    int*   idxB  = (int*)(ws + 15728640);        // 3.15 MB
    float* xn0   = (float*)(ws + 18874368);      // 192 KB
    float* bias0 = (float*)(ws + 19070976);      // 24 KB
    float* bias1 = (float*)(ws + 19095552);      // 24 KB
    float* x0vec = (float*)(ws + 19120128);      // 24 KB
    float* fbuf  = (float*)(ws + 19144704);      // 192 KB
    float* masks = (float*)(ws + 19341312);      // 192 KB
    _Float16* wh0 = (_Float16*)(ws + 19537920);  // 16 KB
    _Float16* wl0 = (_Float16*)(ws + 19554304);  // 16 KB
    _Float16* wh1 = (_Float16*)(ws + 19570688);  // 16 KB
    _Float16* wl1 = (_Float16*)(ws + 19587072);  // 16 KB

    (void)in_sizes; (void)n_in; (void)out_size; (void)ws_size;

    prep_kernel<<<768, 256, 0, stream>>>(x, h0, l0, xn0, w0, w1, wh0, wl0, wh1, wl1);
    knn_kernel<<<768, 256, 0, stream>>>(h0, l0, xn0, nullptr, 0, idxA, 10);
    erase0_kernel<<<96, 256, 0, stream>>>(x, w0, w_erase, b_erase, g_erase, be_erase, m_erase, v_erase, bias0);
    fused_branch_kernel<0><<<dim3(96, 4), 256, 0, stream>>>(h0, l0, wh0, wl0, idxA, nullptr, 0, bias0,
                                                            g0, b0, m0, v0, out, x0vec);
    corre_kernel<<<96, 256, 0, stream>>>(x, x0vec, w_reduce, idxA, fbuf, masks);
    erase1_kernel<<<96, 256, 0, stream>>>(x, masks, fbuf, w_erase, b_erase, g_erase, be_erase, m_erase, v_erase,
                                          w1, bias1);
    knn_kernel<<<768, 256, 0, stream>>>(h0, l0, xn0, masks, 1, idxB, 10);
    fused_branch_kernel<1><<<dim3(96, 4), 256, 0, stream>>>(h0, l0, wh1, wl1, idxB, masks, 1, bias1,
                                                            g1, b1, m1, v1, out, nullptr);
}

// Round 11
// 275.520 us; speedup vs baseline: 1.5271x; 1.1193x over previous
//
#include <hip/hip_runtime.h>
#include <math.h>

#define EPS 1e-5f

typedef _Float16 half8 __attribute__((ext_vector_type(8)));
typedef float f32x4 __attribute__((ext_vector_type(4)));

// H/L global layout per row: [tile(8)][chunk(8)][col(64)] x 8 halves (16B units).

// bq in [0,96): b = bq/12, t = bq%12; x1seq row = b*12 + min(t+1, 11)
__device__ __forceinline__ int src_row(int bq) {
    int b = bq / 12, t = bq - b * 12;
    int t2 = (t + 1 < 12) ? (t + 1) : 11;
    return b * 12 + t2;
}

// ---------------- erase0: y0 = BN(W_e @ mean_n(x) + b_e); bias0 = W2_0 @ y0 ----------------
__global__ __launch_bounds__(256) void erase0_kernel(
    const float* __restrict__ x, const float* __restrict__ w0,
    const float* __restrict__ w_e, const float* __restrict__ b_e,
    const float* __restrict__ g_e, const float* __restrict__ be_e,
    const float* __restrict__ m_e, const float* __restrict__ v_e,
    float* __restrict__ bias0)
{
    __shared__ float part[256];
    __shared__ float res[64];
    __shared__ float sy[64];
    int bq = blockIdx.x, tid = threadIdx.x;
    int c = tid >> 2, p = tid & 3;
    const float* xb = x + (size_t)bq * 32768 + c * 512 + p * 128;
    float acc = 0.f;
    for (int ii = 0; ii < 128; ii += 4) {
        float4 v = *(const float4*)(xb + ii);
        acc += v.x + v.y + v.z + v.w;
    }
    part[tid] = acc;
    __syncthreads();
    if (p == 0) res[c] = (part[tid] + part[tid+1] + part[tid+2] + part[tid+3]) * (1.f/512.f);
    __syncthreads();
    if (tid < 64) {
        float a = b_e[tid];
        for (int cc = 0; cc < 64; ++cc) a += w_e[tid*64+cc] * res[cc];
        float s = g_e[tid] / sqrtf(v_e[tid] + EPS);
        sy[tid] = (a - m_e[tid]) * s + be_e[tid];
    }
    __syncthreads();
    if (tid < 64) {
        float a = 0.f;
        for (int cc = 0; cc < 64; ++cc) a += w0[tid * 128 + 64 + cc] * sy[cc];
        bias0[bq * 64 + tid] = a;
    }
}

// ---------------- prep: fp16 split of raw x (chunk layout) + colnorms + W' splits ----------------
// grid = 768. blockIdx = ct*96 + bq (XCD swizzle).
__global__ __launch_bounds__(256) void prep_kernel(
    const float* __restrict__ X,
    _Float16* __restrict__ H, _Float16* __restrict__ L, float* __restrict__ xn,
    const float* __restrict__ w0, const float* __restrict__ w1,
    _Float16* __restrict__ wh0, _Float16* __restrict__ wl0,
    _Float16* __restrict__ wh1, _Float16* __restrict__ wl1)
{
    __shared__ float lds[64 * 65];
    __shared__ float xnp[4 * 64];
    int raw = blockIdx.x;
    int bq = raw % 96;
    int ct = raw / 96;
    const float* Xb = X + (size_t)bq * 32768 + ct * 64;
    int tid = threadIdx.x;
    for (int p = 0; p < 16; ++p) {
        int t = p * 256 + tid;
        int c = t >> 6, col = t & 63;
        lds[c * 65 + col] = Xb[c * 512 + col];
    }
    __syncthreads();
    int col = tid & 63, g = tid >> 6;
    half8 hv[2], lv[2];
    float s = 0.f;
    #pragma unroll
    for (int k = 0; k < 16; ++k) {
        int c = g * 16 + k;
        float v = lds[c * 65 + col];
        _Float16 h = (_Float16)v;
        _Float16 lo = (_Float16)(v - (float)h);
        hv[k >> 3][k & 7] = h;
        lv[k >> 3][k & 7] = lo;
        s += v * v;
    }
    size_t obase = (size_t)bq * 32768 + ((size_t)(ct * 8 + 2 * g) * 64 + col) * 8;
    *(half8*)(H + obase) = hv[0];
    *(half8*)(H + obase + 512) = hv[1];
    *(half8*)(L + obase) = lv[0];
    *(half8*)(L + obase + 512) = lv[1];
    xnp[g * 64 + col] = s;
    __syncthreads();
    if (tid < 64)
        xn[bq * 512 + ct * 64 + tid] =
            xnp[tid] + xnp[64 + tid] + xnp[128 + tid] + xnp[192 + tid];
    if (raw < 2) {
        const float* W = raw ? w1 : w0;
        _Float16* WH = raw ? wh1 : wh0;
        _Float16* WL = raw ? wl1 : wl0;
        for (int t = tid; t < 8192; t += 256) {
            int o = t >> 6, c = t & 63;
            float v = (o < 64) ? W[o * 128 + c]
                               : (W[(o - 64) * 128 + 64 + c] - W[(o - 64) * 128 + c]);
            _Float16 h = (_Float16)v;
            WH[t] = h;
            WL[t] = (_Float16)(v - (float)h);
        }
    }
}

// ---------------- kNN: LDS-staged tiles + MFMA + value-only sort; MASKED templated ----------------
// grid = 768 = 3 blocks/CU; launch_bounds (256,3) -> 170 VGPR budget, no spills.
template<int MASKED>
__global__ __launch_bounds__(256, 3) void knn_kernel(
    const _Float16* __restrict__ H, const _Float16* __restrict__ L,
    const float* __restrict__ xn, const float* __restrict__ masks, int remap,
    int* __restrict__ idx_out, int K)
{
    __shared__ float4 jbufH4[512];
    __shared__ float4 jbufL4[512];
    __shared__ float smask[512];
    __shared__ unsigned ldsMV[4][64 * 11];
    __shared__ unsigned short ldsMJ[4][64 * 11];
    int raw = blockIdx.x;
    int bq = raw % 96;
    int itile = raw / 96;
    int row = remap ? src_row(bq) : bq;
    int tid = threadIdx.x, w = tid >> 6, l = tid & 63;
    int lane16 = l & 15, quad = l >> 4;
    const size_t base = (size_t)row * 32768;
    const _Float16* Hb = H + base;
    const _Float16* Lb = L + base;
    if (MASKED) {
        smask[tid] = masks[bq * 512 + tid];
        smask[tid + 256] = masks[bq * 512 + tid + 256];
    }
    int irow = itile * 64 + w * 16 + lane16;
    size_t bo = ((size_t)(itile * 8 + quad) * 64 + (w * 16 + lane16)) * 8;
    half8 Bh0 = *(const half8*)(Hb + bo);
    half8 Bh1 = *(const half8*)(Hb + bo + 2048);
    half8 Bl0 = *(const half8*)(Lb + bo);
    half8 Bl1 = *(const half8*)(Lb + bo + 2048);
    if (MASKED) {
        float bm = masks[bq * 512 + irow];
        if (bm == 0.f) {
            half8 z = {};
            Bh0 = z; Bh1 = z; Bl0 = z; Bl1 = z;
        }
    }

    unsigned kv[10]; int kj[10];
    #pragma unroll
    for (int qq = 0; qq < 10; ++qq) { kv[qq] = 0u; kj[qq] = 0; }

    auto casu = [](unsigned& a, unsigned& b) {
        unsigned mn = a < b ? a : b;
        unsigned mx = a < b ? b : a;
        a = mn; b = mx;
    };
    auto cas_kj = [](unsigned& ka, int& ja, unsigned& kb, int& jb2) {
        bool sw = ka > kb;
        unsigned tk = ka; int tj = ja;
        ka = sw ? kb : ka; ja = sw ? jb2 : ja;
        kb = sw ? tk : kb; jb2 = sw ? tj : jb2;
    };

    const float* xnb = xn + row * 512;
    const _Float16* jH = (const _Float16*)jbufH4;
    const _Float16* jL = (const _Float16*)jbufL4;
    float4 pa0, pa1, pb0, pb1;
    {
        const float4* gh = (const float4*)(Hb);
        const float4* gl = (const float4*)(Lb);
        pa0 = gh[tid]; pa1 = gh[256 + tid];
        pb0 = gl[tid]; pb1 = gl[256 + tid];
    }
    if (MASKED) __syncthreads();            // smask visible before first masked stage
    for (int jt = 0; jt < 8; ++jt) {
        if (jt) __syncthreads();
        if (MASKED) {
            float m = smask[jt * 64 + (tid & 63)];
            float4 z4 = {0.f, 0.f, 0.f, 0.f};
            bool on = (m != 0.f);
            jbufH4[tid] = on ? pa0 : z4; jbufH4[256 + tid] = on ? pa1 : z4;
            jbufL4[tid] = on ? pb0 : z4; jbufL4[256 + tid] = on ? pb1 : z4;
        } else {
            jbufH4[tid] = pa0; jbufH4[256 + tid] = pa1;
            jbufL4[tid] = pb0; jbufL4[256 + tid] = pb1;
        }
        __syncthreads();
        if (jt < 7) {
            const float4* gh = (const float4*)(Hb + (jt + 1) * 4096);
            const float4* gl = (const float4*)(Lb + (jt + 1) * 4096);
            pa0 = gh[tid]; pa1 = gh[256 + tid];
            pb0 = gl[tid]; pb1 = gl[256 + tid];
        }
        unsigned d[16];
        #pragma unroll
        for (int g = 0; g < 4; ++g) {
            int u = quad * 64 + g * 16 + lane16;
            half8 Ah0 = *(const half8*)(jH + (size_t)u * 8);
            half8 Ah1 = *(const half8*)(jH + (size_t)u * 8 + 2048);
            half8 Al0 = *(const half8*)(jL + (size_t)u * 8);
            half8 Al1 = *(const half8*)(jL + (size_t)u * 8 + 2048);
            f32x4 acc = {0.f, 0.f, 0.f, 0.f};
            acc = __builtin_amdgcn_mfma_f32_16x16x32_f16(Ah0, Bh0, acc, 0, 0, 0);
            acc = __builtin_amdgcn_mfma_f32_16x16x32_f16(Ah1, Bh1, acc, 0, 0, 0);
            acc = __builtin_amdgcn_mfma_f32_16x16x32_f16(Al0, Bh0, acc, 0, 0, 0);
            acc = __builtin_amdgcn_mfma_f32_16x16x32_f16(Al1, Bh1, acc, 0, 0, 0);
            acc = __builtin_amdgcn_mfma_f32_16x16x32_f16(Ah0, Bl0, acc, 0, 0, 0);
            acc = __builtin_amdgcn_mfma_f32_16x16x32_f16(Ah1, Bl1, acc, 0, 0, 0);
            int jb = jt * 64 + g * 16 + quad * 4;
            float4 xn4 = *(const float4*)&xnb[jb];
            if (MASKED) {
                float4 sm4 = *(const float4*)&smask[jb];
                if (sm4.x == 0.f) xn4.x = 0.f;
                if (sm4.y == 0.f) xn4.y = 0.f;
                if (sm4.z == 0.f) xn4.z = 0.f;
                if (sm4.w == 0.f) xn4.w = 0.f;
            }
            #pragma unroll
            for (int r = 0; r < 4; ++r) {
                float sc = 2.f * acc[r] - (r == 0 ? xn4.x : r == 1 ? xn4.y : r == 2 ? xn4.z : xn4.w);
                int bi = __float_as_int(sc);
                unsigned u2 = (unsigned)(bi ^ ((bi >> 31) | 0x80000000));
                int slot = g * 4 + r;
                d[slot] = (u2 & 0xFFFFFFF0u) | (unsigned)(15 - slot);
            }
        }
        #pragma unroll
        for (int p = 1; p < 16; p <<= 1) {
            #pragma unroll
            for (int k = p; k >= 1; k >>= 1) {
                #pragma unroll
                for (int j = k & (p - 1); j + k < 16; j += 2 * k) {
                    #pragma unroll
                    for (int i = 0; i < k; ++i) {
                        if ((i + j + k < 16) &&
                            ((i + j) / (2 * p) == (i + j + k) / (2 * p)))
                            casu(d[i + j], d[i + j + k]);
                    }
                }
            }
        }
        #pragma unroll
        for (int i = 0; i < 10; ++i) {
            unsigned dv = d[15 - i];
            int code = 15 - (int)(dv & 15u);
            int jnew = jt * 64 + (code >> 2) * 16 + quad * 4 + (code & 3);
            bool keep = kv[i] >= dv;
            kj[i] = keep ? kj[i] : jnew;
            kv[i] = keep ? kv[i] : dv;
        }
        cas_kj(kv[0], kj[0], kv[8], kj[8]);
        cas_kj(kv[1], kj[1], kv[9], kj[9]);
        cas_kj(kv[0], kj[0], kv[4], kj[4]);
        cas_kj(kv[1], kj[1], kv[5], kj[5]);
        cas_kj(kv[2], kj[2], kv[6], kj[6]);
        cas_kj(kv[3], kj[3], kv[7], kj[7]);
        cas_kj(kv[0], kj[0], kv[2], kj[2]);
        cas_kj(kv[1], kj[1], kv[3], kj[3]);
        cas_kj(kv[4], kj[4], kv[6], kj[6]);
        cas_kj(kv[5], kj[5], kv[7], kj[7]);
        cas_kj(kv[0], kj[0], kv[1], kj[1]);
        cas_kj(kv[2], kj[2], kv[3], kj[3]);
        cas_kj(kv[4], kj[4], kv[5], kj[5]);
        cas_kj(kv[6], kj[6], kv[7], kj[7]);
        cas_kj(kv[8], kj[8], kv[9], kj[9]);
    }
    #pragma unroll
    for (int qq = 0; qq < 10; ++qq) {
        ldsMV[w][(lane16 * 4 + quad) * 11 + qq] = kv[qq];
        ldsMJ[w][(lane16 * 4 + quad) * 11 + qq] = (unsigned short)kj[qq];
    }
    __syncthreads();
    if (quad == 0) {
        const unsigned* MV = &ldsMV[w][lane16 * 44];
        const unsigned short* MJ = &ldsMJ[w][lane16 * 44];
        int p0 = 9, p1 = 9, p2 = 9, p3 = 9;
        int* op = idx_out + ((size_t)bq * 512 + irow) * 16;
        for (int t = 0; t < K; ++t) {
            unsigned bv = 0u; int bj = 0x7fffffff; int bc = -1;
            { unsigned v = MV[p0]; int j = MJ[p0];
              if (v > bv || (v == bv && j < bj)) { bv = v; bj = j; bc = 0; } }
            { unsigned v = MV[11 + p1]; int j = MJ[11 + p1];
              if (v > bv || (v == bv && j < bj)) { bv = v; bj = j; bc = 1; } }
            { unsigned v = MV[22 + p2]; int j = MJ[22 + p2];
              if (v > bv || (v == bv && j < bj)) { bv = v; bj = j; bc = 2; } }
            { unsigned v = MV[33 + p3]; int j = MJ[33 + p3];
              if (v > bv || (v == bv && j < bj)) { bv = v; bj = j; bc = 3; } }
            if (bc == 0) --p0; else if (bc == 1) --p1; else if (bc == 2) --p2; else --p3;
            op[t] = bj;
        }
    }
}

// ---------------- fused branch: grid (96,4); optional mask+remap; per-(bq,o) bias ----------------
// LDS 76 KB caps occupancy at 2 blocks/CU; (256,2) claims the matching VGPR budget.
template<int ACC>
__global__ __launch_bounds__(256, 2) void fused_branch_kernel(
    const _Float16* __restrict__ H, const _Float16* __restrict__ L,
    const _Float16* __restrict__ WH, const _Float16* __restrict__ WL,
    const int* __restrict__ idx, const float* __restrict__ masks, int remap,
    const float* __restrict__ bias,
    const float* __restrict__ g, const float* __restrict__ bb,
    const float* __restrict__ mm, const float* __restrict__ vv,
    float* __restrict__ out_p, float* __restrict__ vec_out)
{
    __shared__ float ldsA[16 * 512];
    __shared__ float ldsB[16 * 512];
    __shared__ unsigned short ldsIdx[512 * 10];
    __shared__ float smask[512];
    int bq = blockIdx.x, ob = blockIdx.y * 16;
    int row = remap ? src_row(bq) : bq;
    bool use_mask = (masks != nullptr);
    int tid = threadIdx.x, w = tid >> 6, l = tid & 63;
    int lane16 = l & 15, quad = l >> 4;
    const size_t base = (size_t)row * 32768;
    for (int p = 0; p < 20; ++p) {
        int t = p * 256 + tid;
        int i = t / 10, q = t - i * 10;
        ldsIdx[t] = (unsigned short)idx[((size_t)bq * 512 + i) * 16 + q];
    }
    if (use_mask) {
        smask[tid] = masks[bq * 512 + tid];
        smask[tid + 256] = masks[bq * 512 + tid + 256];
    }
    __syncthreads();
    {
        int part = w & 1;
        int it0 = (w >> 1) * 16;
        int wrow = (part ? 64 + ob : ob) + lane16;
        size_t woff = (size_t)wrow * 64 + quad * 8;
        half8 Ah0 = *(const half8*)(WH + woff);
        half8 Ah1 = *(const half8*)(WH + woff + 32);
        half8 Al0 = *(const half8*)(WL + woff);
        half8 Al1 = *(const half8*)(WL + woff + 32);
        float* dst = part ? ldsB : ldsA;
        for (int k = 0; k < 16; ++k) {
            int it = it0 + k;
            size_t off = base + (((size_t)(it >> 2) * 8 + quad) * 64 + (it & 3) * 16 + lane16) * 8;
            half8 Xh0 = *(const half8*)(H + off);
            half8 Xh1 = *(const half8*)(H + off + 2048);
            half8 Xl0 = *(const half8*)(L + off);
            half8 Xl1 = *(const half8*)(L + off + 2048);
            if (use_mask) {
                float m = smask[it * 16 + lane16];
                if (m == 0.f) {
                    half8 z = {};
                    Xh0 = z; Xh1 = z; Xl0 = z; Xl1 = z;
                }
            }
            f32x4 acc = {0.f, 0.f, 0.f, 0.f};
            acc = __builtin_amdgcn_mfma_f32_16x16x32_f16(Ah0, Xh0, acc, 0, 0, 0);
            acc = __builtin_amdgcn_mfma_f32_16x16x32_f16(Ah1, Xh1, acc, 0, 0, 0);
            acc = __builtin_amdgcn_mfma_f32_16x16x32_f16(Ah0, Xl0, acc, 0, 0, 0);
            acc = __builtin_amdgcn_mfma_f32_16x16x32_f16(Ah1, Xl1, acc, 0, 0, 0);
            acc = __builtin_amdgcn_mfma_f32_16x16x32_f16(Al0, Xh0, acc, 0, 0, 0);
            acc = __builtin_amdgcn_mfma_f32_16x16x32_f16(Al1, Xh1, acc, 0, 0, 0);
            #pragma unroll
            for (int r = 0; r < 4; ++r)
                dst[(quad * 4 + r) * 512 + it * 16 + lane16] = acc[r];
        }
    }
    __syncthreads();
    float ssr[4], str[4];
    #pragma unroll
    for (int oo = 0; oo < 4; ++oo) {
        int o = ob + w * 4 + oo;
        float sc = g[o] / sqrtf(vv[o] + EPS);
        ssr[oo] = sc;
        str[oo] = bb[o] - mm[o] * sc + bias[bq * 64 + o] * sc;
    }
    float omax[4], osum[4];
    #pragma unroll
    for (int oo = 0; oo < 4; ++oo) { omax[oo] = -3.4e38f; osum[oo] = 0.f; }
    const float* Aw = ldsA + (w * 4) * 512;
    const float* Bw = ldsB + (w * 4) * 512;
    for (int s = 0; s < 8; ++s) {
        int i = l + 64 * s;
        int idr[10];
        const unsigned short* ip = &ldsIdx[i * 10];
        #pragma unroll
        for (int q = 0; q < 10; ++q) idr[q] = ip[q];
        #pragma unroll
        for (int oo = 0; oo < 4; ++oo) {
            const float* Ao = Aw + oo * 512;
            float mx = Ao[idr[0]];
            #pragma unroll
            for (int q = 1; q < 10; ++q) mx = fmaxf(mx, Ao[idr[q]]);
            float val = (mx + Bw[oo * 512 + i]) * ssr[oo] + str[oo];
            float y = val > 0.f ? val : 0.2f * val;
            omax[oo] = fmaxf(omax[oo], y);
            osum[oo] += y;
        }
    }
    #pragma unroll
    for (int oo = 0; oo < 4; ++oo) {
        float M = omax[oo], S = osum[oo];
        #pragma unroll
        for (int off = 32; off >= 1; off >>= 1) {
            M = fmaxf(M, __shfl_down(M, off));
            S += __shfl_down(S, off);
        }
        if (l == 0) {
            int o = ob + w * 4 + oo;
            float* po = out_p + bq * 128;
            if (ACC) {
                po[o] += M;
                po[64 + o] += S * (1.f / 512.f);
            } else {
                po[o] = M;
                po[64 + o] = S * (1.f / 512.f);
                vec_out[bq * 64 + o] = M;
            }
        }
    }
}

// ---------------- corre_binar: f, masks (idx8 = prefix-8 of idxA[src_row(bq)]) ----------------
__global__ __launch_bounds__(256) void corre_kernel(
    const float* __restrict__ x, const float* __restrict__ x0vec,
    const float* __restrict__ w_reduce, const int* __restrict__ idxA,
    float* __restrict__ fbuf, float* __restrict__ masks)
{
    __shared__ float sxv[64], sq[64], ss[512], sfk[512];
    int bq = blockIdx.x, tid = threadIdx.x;
    int row = src_row(bq);
    const float* Xb = x + (size_t)row * 32768;
    if (tid < 64) sxv[tid] = x0vec[bq * 64 + tid];
    __syncthreads();
    if (tid < 64) {
        float a = 0.f;
        for (int c = 0; c < 64; ++c) a += w_reduce[tid * 64 + c] * sxv[c];
        sq[tid] = a;
    }
    __syncthreads();
    for (int i = tid; i < 512; i += 256) {
        float a = 0.f;
        for (int c = 0; c < 64; ++c) a += sq[c] * Xb[c * 512 + i];
        a *= 0.125f;
        ss[i] = a;
        fbuf[bq * 512 + i] = a;
    }
    __syncthreads();
    for (int i = tid; i < 512; i += 256) {
        float a = ss[i];
        const int* ip = idxA + ((size_t)row * 512 + i) * 16;
        for (int q = 0; q < 8; ++q) a += ss[ip[q]];
        sfk[i] = a;
    }
    masks[bq * 512 + tid] = 1.0f;
    masks[bq * 512 + tid + 256] = 1.0f;
    __syncthreads();
    if (tid == 0) {
        float best = sfk[0]; int bi = 0;
        for (int i = 1; i < 512; ++i) if (sfk[i] > best) { best = sfk[i]; bi = i; }
        masks[bq * 512 + bi] = 0.f;
        const int* ip = idxA + ((size_t)row * 512 + bi) * 16;
        for (int q = 0; q < 8; ++q) masks[bq * 512 + ip[q]] = 0.f;
    }
}

// ---------------- erase1 slim: y1 = BN(W_e @ softmax-pooled + b_e); bias1 = W2_1 @ y1 ----------------
__global__ __launch_bounds__(256) void erase1_kernel(
    const float* __restrict__ x, const float* __restrict__ masks,
    const float* __restrict__ fbuf,
    const float* __restrict__ w_e, const float* __restrict__ b_e,
    const float* __restrict__ g_e, const float* __restrict__ be_e,
    const float* __restrict__ m_e, const float* __restrict__ v_e,
    const float* __restrict__ w1, float* __restrict__ bias1)
{
    __shared__ float sw[512];
    __shared__ float red[256];
    __shared__ float sres[64];
    __shared__ float sy[64];
    int bq = blockIdx.x, tid = threadIdx.x;
    int row = src_row(bq);
    const float* Xb = x + (size_t)row * 32768;
    float f0 = fbuf[bq * 512 + tid], f1 = fbuf[bq * 512 + tid + 256];
    float mk0 = masks[bq * 512 + tid], mk1 = masks[bq * 512 + tid + 256];
    float s0 = f0 - (1.f - mk0) * 1e8f, s1 = f1 - (1.f - mk1) * 1e8f;
    red[tid] = fmaxf(s0, s1);
    __syncthreads();
    for (int off = 128; off >= 1; off >>= 1) {
        if (tid < off) red[tid] = fmaxf(red[tid], red[tid + off]);
        __syncthreads();
    }
    float mx = red[0];
    __syncthreads();
    float e0 = expf(s0 - mx), e1 = expf(s1 - mx);
    red[tid] = e0 + e1;
    __syncthreads();
    for (int off = 128; off >= 1; off >>= 1) {
        if (tid < off) red[tid] = red[tid] + red[tid + off];
        __syncthreads();
    }
    float inv = 1.f / red[0];
    __syncthreads();
    sw[tid] = e0 * inv; sw[tid + 256] = e1 * inv;
    __syncthreads();
    int c4 = tid >> 2, p4 = tid & 3;
    {
        float a = 0.f;
        const float* xr = Xb + c4 * 512 + p4 * 128;
        const float* wr = &sw[p4 * 128];
        for (int ii = 0; ii < 128; ++ii) a += xr[ii] * wr[ii];
        red[tid] = a;
    }
    __syncthreads();
    if (p4 == 0) sres[c4] = red[tid] + red[tid + 1] + red[tid + 2] + red[tid + 3];
    __syncthreads();
    if (tid < 64) {
        float a = b_e[tid];
        for (int cc = 0; cc < 64; ++cc) a += w_e[tid * 64 + cc] * sres[cc];
        float sc = g_e[tid] / sqrtf(v_e[tid] + EPS);
        sy[tid] = (a - m_e[tid]) * sc + be_e[tid];
    }
    __syncthreads();
    if (tid < 64) {
        float a = 0.f;
        for (int cc = 0; cc < 64; ++cc) a += w1[tid * 128 + 64 + cc] * sy[cc];
        bias1[bq * 64 + tid] = a;
    }
}

extern "C" void kernel_launch(void* const* d_in, const int* in_sizes, int n_in,
                              void* d_out, int out_size, void* d_ws, size_t ws_size,
                              hipStream_t stream)
{
    const float* x        = (const float*)d_in[0];
    const float* w_reduce = (const float*)d_in[1];
    const float* w_erase  = (const float*)d_in[2];
    const float* b_erase  = (const float*)d_in[3];
    const float* g_erase  = (const float*)d_in[4];
    const float* be_erase = (const float*)d_in[5];
    const float* m_erase  = (const float*)d_in[6];
    const float* v_erase  = (const float*)d_in[7];
    const float* w0 = (const float*)d_in[8];
    const float* g0 = (const float*)d_in[9];
    const float* b0 = (const float*)d_in[10];
    const float* m0 = (const float*)d_in[11];
    const float* v0 = (const float*)d_in[12];
    const float* w1 = (const float*)d_in[13];
    const float* g1 = (const float*)d_in[14];
    const float* b1 = (const float*)d_in[15];
    const float* m1 = (const float*)d_in[16];
    const float* v1 = (const float*)d_in[17];
    float* out = (float*)d_out;
    char* ws = (char*)d_ws;

    _Float16* h0 = (_Float16*)(ws);              // 6.29 MB  split of raw x
    _Float16* l0 = (_Float16*)(ws + 6291456);    // 6.29 MB
    int*   idxA  = (int*)(ws + 12582912);        // 3.15 MB
    int*   idxB  = (int*)(ws + 15728640);        // 3.15 MB
    float* xn0   = (float*)(ws + 18874368);      // 192 KB
    float* bias0 = (float*)(ws + 19070976);      // 24 KB
    float* bias1 = (float*)(ws + 19095552);      // 24 KB
    float* x0vec = (float*)(ws + 19120128);      // 24 KB
    float* fbuf  = (float*)(ws + 19144704);      // 192 KB
    float* masks = (float*)(ws + 19341312);      // 192 KB
    _Float16* wh0 = (_Float16*)(ws + 19537920);  // 16 KB
    _Float16* wl0 = (_Float16*)(ws + 19554304);  // 16 KB
    _Float16* wh1 = (_Float16*)(ws + 19570688);  // 16 KB
    _Float16* wl1 = (_Float16*)(ws + 19587072);  // 16 KB

    (void)in_sizes; (void)n_in; (void)out_size; (void)ws_size;

    prep_kernel<<<768, 256, 0, stream>>>(x, h0, l0, xn0, w0, w1, wh0, wl0, wh1, wl1);
    knn_kernel<0><<<768, 256, 0, stream>>>(h0, l0, xn0, nullptr, 0, idxA, 10);
    erase0_kernel<<<96, 256, 0, stream>>>(x, w0, w_erase, b_erase, g_erase, be_erase, m_erase, v_erase, bias0);
    fused_branch_kernel<0><<<dim3(96, 4), 256, 0, stream>>>(h0, l0, wh0, wl0, idxA, nullptr, 0, bias0,
                                                            g0, b0, m0, v0, out, x0vec);
    corre_kernel<<<96, 256, 0, stream>>>(x, x0vec, w_reduce, idxA, fbuf, masks);
    erase1_kernel<<<96, 256, 0, stream>>>(x, masks, fbuf, w_erase, b_erase, g_erase, be_erase, m_erase, v_erase,
                                          w1, bias1);
    knn_kernel<1><<<768, 256, 0, stream>>>(h0, l0, xn0, masks, 1, idxB, 10);
    fused_branch_kernel<1><<<dim3(96, 4), 256, 0, stream>>>(h0, l0, wh1, wl1, idxB, masks, 1, bias1,
                                                            g1, b1, m1, v1, out, nullptr);
}

// Round 12
// 268.164 us; speedup vs baseline: 1.5690x; 1.0274x over previous
//
#include <hip/hip_runtime.h>
#include <math.h>

#define EPS 1e-5f

typedef _Float16 half8 __attribute__((ext_vector_type(8)));
typedef float f32x4 __attribute__((ext_vector_type(4)));

// H/L global layout per row: [tile(8)][chunk(8)][col(64)] x 8 halves (16B units).

// bq in [0,96): b = bq/12, t = bq%12; x1seq row = b*12 + min(t+1, 11)
__device__ __forceinline__ int src_row(int bq) {
    int b = bq / 12, t = bq - b * 12;
    int t2 = (t + 1 < 12) ? (t + 1) : 11;
    return b * 12 + t2;
}

// ---------------- erase0: y0 = BN(W_e @ mean_n(x) + b_e); bias0 = W2_0 @ y0 ----------------
__global__ __launch_bounds__(256) void erase0_kernel(
    const float* __restrict__ x, const float* __restrict__ w0,
    const float* __restrict__ w_e, const float* __restrict__ b_e,
    const float* __restrict__ g_e, const float* __restrict__ be_e,
    const float* __restrict__ m_e, const float* __restrict__ v_e,
    float* __restrict__ bias0)
{
    __shared__ float part[256];
    __shared__ float res[64];
    __shared__ float sy[64];
    int bq = blockIdx.x, tid = threadIdx.x;
    int c = tid >> 2, p = tid & 3;
    const float* xb = x + (size_t)bq * 32768 + c * 512 + p * 128;
    float acc = 0.f;
    for (int ii = 0; ii < 128; ii += 4) {
        float4 v = *(const float4*)(xb + ii);
        acc += v.x + v.y + v.z + v.w;
    }
    part[tid] = acc;
    __syncthreads();
    if (p == 0) res[c] = (part[tid] + part[tid+1] + part[tid+2] + part[tid+3]) * (1.f/512.f);
    __syncthreads();
    if (tid < 64) {
        float a = b_e[tid];
        for (int cc = 0; cc < 64; ++cc) a += w_e[tid*64+cc] * res[cc];
        float s = g_e[tid] / sqrtf(v_e[tid] + EPS);
        sy[tid] = (a - m_e[tid]) * s + be_e[tid];
    }
    __syncthreads();
    if (tid < 64) {
        float a = 0.f;
        for (int cc = 0; cc < 64; ++cc) a += w0[tid * 128 + 64 + cc] * sy[cc];
        bias0[bq * 64 + tid] = a;
    }
}

// ---------------- prep: fp16 split of raw x (chunk layout) + colnorms + W' splits ----------------
// grid = 768. blockIdx = ct*96 + bq (XCD swizzle).
__global__ __launch_bounds__(256) void prep_kernel(
    const float* __restrict__ X,
    _Float16* __restrict__ H, _Float16* __restrict__ L, float* __restrict__ xn,
    const float* __restrict__ w0, const float* __restrict__ w1,
    _Float16* __restrict__ wh0, _Float16* __restrict__ wl0,
    _Float16* __restrict__ wh1, _Float16* __restrict__ wl1)
{
    __shared__ float lds[64 * 65];
    __shared__ float xnp[4 * 64];
    int raw = blockIdx.x;
    int bq = raw % 96;
    int ct = raw / 96;
    const float* Xb = X + (size_t)bq * 32768 + ct * 64;
    int tid = threadIdx.x;
    for (int p = 0; p < 16; ++p) {
        int t = p * 256 + tid;
        int c = t >> 6, col = t & 63;
        lds[c * 65 + col] = Xb[c * 512 + col];
    }
    __syncthreads();
    int col = tid & 63, g = tid >> 6;
    half8 hv[2], lv[2];
    float s = 0.f;
    #pragma unroll
    for (int k = 0; k < 16; ++k) {
        int c = g * 16 + k;
        float v = lds[c * 65 + col];
        _Float16 h = (_Float16)v;
        _Float16 lo = (_Float16)(v - (float)h);
        hv[k >> 3][k & 7] = h;
        lv[k >> 3][k & 7] = lo;
        s += v * v;
    }
    size_t obase = (size_t)bq * 32768 + ((size_t)(ct * 8 + 2 * g) * 64 + col) * 8;
    *(half8*)(H + obase) = hv[0];
    *(half8*)(H + obase + 512) = hv[1];
    *(half8*)(L + obase) = lv[0];
    *(half8*)(L + obase + 512) = lv[1];
    xnp[g * 64 + col] = s;
    __syncthreads();
    if (tid < 64)
        xn[bq * 512 + ct * 64 + tid] =
            xnp[tid] + xnp[64 + tid] + xnp[128 + tid] + xnp[192 + tid];
    if (raw < 2) {
        const float* W = raw ? w1 : w0;
        _Float16* WH = raw ? wh1 : wh0;
        _Float16* WL = raw ? wl1 : wl0;
        for (int t = tid; t < 8192; t += 256) {
            int o = t >> 6, c = t & 63;
            float v = (o < 64) ? W[o * 128 + c]
                               : (W[(o - 64) * 128 + 64 + c] - W[(o - 64) * 128 + c]);
            _Float16 h = (_Float16)v;
            WH[t] = h;
            WL[t] = (_Float16)(v - (float)h);
        }
    }
}

// ---------------- kNN: LDS-staged tiles + MFMA + value-only sort; MASKED templated ----------------
// grid = 768 = 3 blocks/CU. amdgpu_waves_per_eu(3,4): max 4 waves/EU -> 128-reg budget,
// allocator has no occupancy incentive to spill (R11's launch_bounds min-only spilled to 52).
template<int MASKED>
__global__ void __attribute__((amdgpu_flat_work_group_size(256, 256), amdgpu_waves_per_eu(3, 4)))
knn_kernel(
    const _Float16* __restrict__ H, const _Float16* __restrict__ L,
    const float* __restrict__ xn, const float* __restrict__ masks, int remap,
    int* __restrict__ idx_out, int K)
{
    __shared__ float4 jbufH4[512];
    __shared__ float4 jbufL4[512];
    __shared__ float smask[512];
    __shared__ unsigned ldsMV[4][64 * 11];
    __shared__ unsigned short ldsMJ[4][64 * 11];
    int raw = blockIdx.x;
    int bq = raw % 96;
    int itile = raw / 96;
    int row = remap ? src_row(bq) : bq;
    int tid = threadIdx.x, w = tid >> 6, l = tid & 63;
    int lane16 = l & 15, quad = l >> 4;
    const size_t base = (size_t)row * 32768;
    const _Float16* Hb = H + base;
    const _Float16* Lb = L + base;
    if (MASKED) {
        smask[tid] = masks[bq * 512 + tid];
        smask[tid + 256] = masks[bq * 512 + tid + 256];
    }
    int irow = itile * 64 + w * 16 + lane16;
    size_t bo = ((size_t)(itile * 8 + quad) * 64 + (w * 16 + lane16)) * 8;
    half8 Bh0 = *(const half8*)(Hb + bo);
    half8 Bh1 = *(const half8*)(Hb + bo + 2048);
    half8 Bl0 = *(const half8*)(Lb + bo);
    half8 Bl1 = *(const half8*)(Lb + bo + 2048);
    if (MASKED) {
        float bm = masks[bq * 512 + irow];
        if (bm == 0.f) {
            half8 z = {};
            Bh0 = z; Bh1 = z; Bl0 = z; Bl1 = z;
        }
    }

    unsigned kv[10]; int kj[10];
    #pragma unroll
    for (int qq = 0; qq < 10; ++qq) { kv[qq] = 0u; kj[qq] = 0; }

    auto casu = [](unsigned& a, unsigned& b) {
        unsigned mn = a < b ? a : b;
        unsigned mx = a < b ? b : a;
        a = mn; b = mx;
    };
    auto cas_kj = [](unsigned& ka, int& ja, unsigned& kb, int& jb2) {
        bool sw = ka > kb;
        unsigned tk = ka; int tj = ja;
        ka = sw ? kb : ka; ja = sw ? jb2 : ja;
        kb = sw ? tk : kb; jb2 = sw ? tj : jb2;
    };

    const float* xnb = xn + row * 512;
    const _Float16* jH = (const _Float16*)jbufH4;
    const _Float16* jL = (const _Float16*)jbufL4;
    float4 pa0, pa1, pb0, pb1;
    {
        const float4* gh = (const float4*)(Hb);
        const float4* gl = (const float4*)(Lb);
        pa0 = gh[tid]; pa1 = gh[256 + tid];
        pb0 = gl[tid]; pb1 = gl[256 + tid];
    }
    if (MASKED) __syncthreads();            // smask visible before first masked stage
    for (int jt = 0; jt < 8; ++jt) {
        if (jt) __syncthreads();
        if (MASKED) {
            float m = smask[jt * 64 + (tid & 63)];
            float4 z4 = {0.f, 0.f, 0.f, 0.f};
            bool on = (m != 0.f);
            jbufH4[tid] = on ? pa0 : z4; jbufH4[256 + tid] = on ? pa1 : z4;
            jbufL4[tid] = on ? pb0 : z4; jbufL4[256 + tid] = on ? pb1 : z4;
        } else {
            jbufH4[tid] = pa0; jbufH4[256 + tid] = pa1;
            jbufL4[tid] = pb0; jbufL4[256 + tid] = pb1;
        }
        __syncthreads();
        if (jt < 7) {
            const float4* gh = (const float4*)(Hb + (jt + 1) * 4096);
            const float4* gl = (const float4*)(Lb + (jt + 1) * 4096);
            pa0 = gh[tid]; pa1 = gh[256 + tid];
            pb0 = gl[tid]; pb1 = gl[256 + tid];
        }
        unsigned d[16];
        #pragma unroll
        for (int g = 0; g < 4; ++g) {
            int u = quad * 64 + g * 16 + lane16;
            half8 Ah0 = *(const half8*)(jH + (size_t)u * 8);
            half8 Ah1 = *(const half8*)(jH + (size_t)u * 8 + 2048);
            half8 Al0 = *(const half8*)(jL + (size_t)u * 8);
            half8 Al1 = *(const half8*)(jL + (size_t)u * 8 + 2048);
            f32x4 acc = {0.f, 0.f, 0.f, 0.f};
            acc = __builtin_amdgcn_mfma_f32_16x16x32_f16(Ah0, Bh0, acc, 0, 0, 0);
            acc = __builtin_amdgcn_mfma_f32_16x16x32_f16(Ah1, Bh1, acc, 0, 0, 0);
            acc = __builtin_amdgcn_mfma_f32_16x16x32_f16(Al0, Bh0, acc, 0, 0, 0);
            acc = __builtin_amdgcn_mfma_f32_16x16x32_f16(Al1, Bh1, acc, 0, 0, 0);
            acc = __builtin_amdgcn_mfma_f32_16x16x32_f16(Ah0, Bl0, acc, 0, 0, 0);
            acc = __builtin_amdgcn_mfma_f32_16x16x32_f16(Ah1, Bl1, acc, 0, 0, 0);
            int jb = jt * 64 + g * 16 + quad * 4;
            float4 xn4 = *(const float4*)&xnb[jb];
            if (MASKED) {
                float4 sm4 = *(const float4*)&smask[jb];
                if (sm4.x == 0.f) xn4.x = 0.f;
                if (sm4.y == 0.f) xn4.y = 0.f;
                if (sm4.z == 0.f) xn4.z = 0.f;
                if (sm4.w == 0.f) xn4.w = 0.f;
            }
            #pragma unroll
            for (int r = 0; r < 4; ++r) {
                float sc = 2.f * acc[r] - (r == 0 ? xn4.x : r == 1 ? xn4.y : r == 2 ? xn4.z : xn4.w);
                int bi = __float_as_int(sc);
                unsigned u2 = (unsigned)(bi ^ ((bi >> 31) | 0x80000000));
                int slot = g * 4 + r;
                d[slot] = (u2 & 0xFFFFFFF0u) | (unsigned)(15 - slot);
            }
        }
        #pragma unroll
        for (int p = 1; p < 16; p <<= 1) {
            #pragma unroll
            for (int k = p; k >= 1; k >>= 1) {
                #pragma unroll
                for (int j = k & (p - 1); j + k < 16; j += 2 * k) {
                    #pragma unroll
                    for (int i = 0; i < k; ++i) {
                        if ((i + j + k < 16) &&
                            ((i + j) / (2 * p) == (i + j + k) / (2 * p)))
                            casu(d[i + j], d[i + j + k]);
                    }
                }
            }
        }
        #pragma unroll
        for (int i = 0; i < 10; ++i) {
            unsigned dv = d[15 - i];
            int code = 15 - (int)(dv & 15u);
            int jnew = jt * 64 + (code >> 2) * 16 + quad * 4 + (code & 3);
            bool keep = kv[i] >= dv;
            kj[i] = keep ? kj[i] : jnew;
            kv[i] = keep ? kv[i] : dv;
        }
        cas_kj(kv[0], kj[0], kv[8], kj[8]);
        cas_kj(kv[1], kj[1], kv[9], kj[9]);
        cas_kj(kv[0], kj[0], kv[4], kj[4]);
        cas_kj(kv[1], kj[1], kv[5], kj[5]);
        cas_kj(kv[2], kj[2], kv[6], kj[6]);
        cas_kj(kv[3], kj[3], kv[7], kj[7]);
        cas_kj(kv[0], kj[0], kv[2], kj[2]);
        cas_kj(kv[1], kj[1], kv[3], kj[3]);
        cas_kj(kv[4], kj[4], kv[6], kj[6]);
        cas_kj(kv[5], kj[5], kv[7], kj[7]);
        cas_kj(kv[0], kj[0], kv[1], kj[1]);
        cas_kj(kv[2], kj[2], kv[3], kj[3]);
        cas_kj(kv[4], kj[4], kv[5], kj[5]);
        cas_kj(kv[6], kj[6], kv[7], kj[7]);
        cas_kj(kv[8], kj[8], kv[9], kj[9]);
    }
    #pragma unroll
    for (int qq = 0; qq < 10; ++qq) {
        ldsMV[w][(lane16 * 4 + quad) * 11 + qq] = kv[qq];
        ldsMJ[w][(lane16 * 4 + quad) * 11 + qq] = (unsigned short)kj[qq];
    }
    __syncthreads();
    if (quad == 0) {
        const unsigned* MV = &ldsMV[w][lane16 * 44];
        const unsigned short* MJ = &ldsMJ[w][lane16 * 44];
        int p0 = 9, p1 = 9, p2 = 9, p3 = 9;
        int* op = idx_out + ((size_t)bq * 512 + irow) * 16;
        for (int t = 0; t < K; ++t) {
            unsigned bv = 0u; int bj = 0x7fffffff; int bc = -1;
            { unsigned v = MV[p0]; int j = MJ[p0];
              if (v > bv || (v == bv && j < bj)) { bv = v; bj = j; bc = 0; } }
            { unsigned v = MV[11 + p1]; int j = MJ[11 + p1];
              if (v > bv || (v == bv && j < bj)) { bv = v; bj = j; bc = 1; } }
            { unsigned v = MV[22 + p2]; int j = MJ[22 + p2];
              if (v > bv || (v == bv && j < bj)) { bv = v; bj = j; bc = 2; } }
            { unsigned v = MV[33 + p3]; int j = MJ[33 + p3];
              if (v > bv || (v == bv && j < bj)) { bv = v; bj = j; bc = 3; } }
            if (bc == 0) --p0; else if (bc == 1) --p1; else if (bc == 2) --p2; else --p3;
            op[t] = bj;
        }
    }
}

// ---------------- fused branch v3: grid (96,8), 8 o's per block, LDS 44 KB -> 3 blocks/CU ----
// Phase1: one 16-row W' tile [A rows ob..ob+7 ; B rows 64+ob..64+ob+7]; wave w does
// i-tiles w*8..w*8+7. Phase2: wave w reduces o's ob+2w, ob+2w+1.
template<int ACC>
__global__ void __attribute__((amdgpu_flat_work_group_size(256, 256), amdgpu_waves_per_eu(2, 4)))
fused_branch_kernel(
    const _Float16* __restrict__ H, const _Float16* __restrict__ L,
    const _Float16* __restrict__ WH, const _Float16* __restrict__ WL,
    const int* __restrict__ idx, const float* __restrict__ masks, int remap,
    const float* __restrict__ bias,
    const float* __restrict__ g, const float* __restrict__ bb,
    const float* __restrict__ mm, const float* __restrict__ vv,
    float* __restrict__ out_p, float* __restrict__ vec_out)
{
    __shared__ float ldsA[8 * 512];            // 16 KB
    __shared__ float ldsB[8 * 512];            // 16 KB
    __shared__ unsigned short ldsIdx[512 * 10]; // 10 KB
    __shared__ float smask[512];               // 2 KB
    int bq = blockIdx.x, ob = blockIdx.y * 8;
    int row = remap ? src_row(bq) : bq;
    bool use_mask = (masks != nullptr);
    int tid = threadIdx.x, w = tid >> 6, l = tid & 63;
    int lane16 = l & 15, quad = l >> 4;
    const size_t base = (size_t)row * 32768;
    for (int p = 0; p < 20; ++p) {
        int t = p * 256 + tid;
        int i = t / 10, q = t - i * 10;
        ldsIdx[t] = (unsigned short)idx[((size_t)bq * 512 + i) * 16 + q];
    }
    if (use_mask) {
        smask[tid] = masks[bq * 512 + tid];
        smask[tid + 256] = masks[bq * 512 + tid + 256];
    }
    __syncthreads();
    {
        int wrow = (lane16 < 8) ? (ob + lane16) : (64 + ob + (lane16 - 8));
        size_t woff = (size_t)wrow * 64 + quad * 8;
        half8 Ah0 = *(const half8*)(WH + woff);
        half8 Ah1 = *(const half8*)(WH + woff + 32);
        half8 Al0 = *(const half8*)(WL + woff);
        half8 Al1 = *(const half8*)(WL + woff + 32);
        float* dst = (quad < 2) ? (ldsA + (quad * 4) * 512) : (ldsB + ((quad - 2) * 4) * 512);
        for (int k = 0; k < 8; ++k) {
            int it = w * 8 + k;
            size_t off = base + (((size_t)(it >> 2) * 8 + quad) * 64 + (it & 3) * 16 + lane16) * 8;
            half8 Xh0 = *(const half8*)(H + off);
            half8 Xh1 = *(const half8*)(H + off + 2048);
            half8 Xl0 = *(const half8*)(L + off);
            half8 Xl1 = *(const half8*)(L + off + 2048);
            if (use_mask) {
                float m = smask[it * 16 + lane16];
                if (m == 0.f) {
                    half8 z = {};
                    Xh0 = z; Xh1 = z; Xl0 = z; Xl1 = z;
                }
            }
            f32x4 acc = {0.f, 0.f, 0.f, 0.f};
            acc = __builtin_amdgcn_mfma_f32_16x16x32_f16(Ah0, Xh0, acc, 0, 0, 0);
            acc = __builtin_amdgcn_mfma_f32_16x16x32_f16(Ah1, Xh1, acc, 0, 0, 0);
            acc = __builtin_amdgcn_mfma_f32_16x16x32_f16(Ah0, Xl0, acc, 0, 0, 0);
            acc = __builtin_amdgcn_mfma_f32_16x16x32_f16(Ah1, Xl1, acc, 0, 0, 0);
            acc = __builtin_amdgcn_mfma_f32_16x16x32_f16(Al0, Xh0, acc, 0, 0, 0);
            acc = __builtin_amdgcn_mfma_f32_16x16x32_f16(Al1, Xh1, acc, 0, 0, 0);
            #pragma unroll
            for (int r = 0; r < 4; ++r)
                dst[r * 512 + it * 16 + lane16] = acc[r];
        }
    }
    __syncthreads();
    float ssr[2], str[2];
    #pragma unroll
    for (int oo = 0; oo < 2; ++oo) {
        int o = ob + w * 2 + oo;
        float sc = g[o] / sqrtf(vv[o] + EPS);
        ssr[oo] = sc;
        str[oo] = bb[o] - mm[o] * sc + bias[bq * 64 + o] * sc;
    }
    float omax[2], osum[2];
    #pragma unroll
    for (int oo = 0; oo < 2; ++oo) { omax[oo] = -3.4e38f; osum[oo] = 0.f; }
    const float* Aw = ldsA + (w * 2) * 512;
    const float* Bw = ldsB + (w * 2) * 512;
    for (int s = 0; s < 8; ++s) {
        int i = l + 64 * s;
        int idr[10];
        const unsigned short* ip = &ldsIdx[i * 10];
        #pragma unroll
        for (int q = 0; q < 10; ++q) idr[q] = ip[q];
        #pragma unroll
        for (int oo = 0; oo < 2; ++oo) {
            const float* Ao = Aw + oo * 512;
            float mx = Ao[idr[0]];
            #pragma unroll
            for (int q = 1; q < 10; ++q) mx = fmaxf(mx, Ao[idr[q]]);
            float val = (mx + Bw[oo * 512 + i]) * ssr[oo] + str[oo];
            float y = val > 0.f ? val : 0.2f * val;
            omax[oo] = fmaxf(omax[oo], y);
            osum[oo] += y;
        }
    }
    #pragma unroll
    for (int oo = 0; oo < 2; ++oo) {
        float M = omax[oo], S = osum[oo];
        #pragma unroll
        for (int off = 32; off >= 1; off >>= 1) {
            M = fmaxf(M, __shfl_down(M, off));
            S += __shfl_down(S, off);
        }
        if (l == 0) {
            int o = ob + w * 2 + oo;
            float* po = out_p + bq * 128;
            if (ACC) {
                po[o] += M;
                po[64 + o] += S * (1.f / 512.f);
            } else {
                po[o] = M;
                po[64 + o] = S * (1.f / 512.f);
                vec_out[bq * 64 + o] = M;
            }
        }
    }
}

// ---------------- corre_binar: f, masks (idx8 = prefix-8 of idxA[src_row(bq)]) ----------------
__global__ __launch_bounds__(256) void corre_kernel(
    const float* __restrict__ x, const float* __restrict__ x0vec,
    const float* __restrict__ w_reduce, const int* __restrict__ idxA,
    float* __restrict__ fbuf, float* __restrict__ masks)
{
    __shared__ float sxv[64], sq[64], ss[512], sfk[512];
    int bq = blockIdx.x, tid = threadIdx.x;
    int row = src_row(bq);
    const float* Xb = x + (size_t)row * 32768;
    if (tid < 64) sxv[tid] = x0vec[bq * 64 + tid];
    __syncthreads();
    if (tid < 64) {
        float a = 0.f;
        for (int c = 0; c < 64; ++c) a += w_reduce[tid * 64 + c] * sxv[c];
        sq[tid] = a;
    }
    __syncthreads();
    for (int i = tid; i < 512; i += 256) {
        float a = 0.f;
        for (int c = 0; c < 64; ++c) a += sq[c] * Xb[c * 512 + i];
        a *= 0.125f;
        ss[i] = a;
        fbuf[bq * 512 + i] = a;
    }
    __syncthreads();
    for (int i = tid; i < 512; i += 256) {
        float a = ss[i];
        const int* ip = idxA + ((size_t)row * 512 + i) * 16;
        for (int q = 0; q < 8; ++q) a += ss[ip[q]];
        sfk[i] = a;
    }
    masks[bq * 512 + tid] = 1.0f;
    masks[bq * 512 + tid + 256] = 1.0f;
    __syncthreads();
    if (tid == 0) {
        float best = sfk[0]; int bi = 0;
        for (int i = 1; i < 512; ++i) if (sfk[i] > best) { best = sfk[i]; bi = i; }
        masks[bq * 512 + bi] = 0.f;
        const int* ip = idxA + ((size_t)row * 512 + bi) * 16;
        for (int q = 0; q < 8; ++q) masks[bq * 512 + ip[q]] = 0.f;
    }
}

// ---------------- erase1 slim: y1 = BN(W_e @ softmax-pooled + b_e); bias1 = W2_1 @ y1 ----------------
__global__ __launch_bounds__(256) void erase1_kernel(
    const float* __restrict__ x, const float* __restrict__ masks,
    const float* __restrict__ fbuf,
    const float* __restrict__ w_e, const float* __restrict__ b_e,
    const float* __restrict__ g_e, const float* __restrict__ be_e,
    const float* __restrict__ m_e, const float* __restrict__ v_e,
    const float* __restrict__ w1, float* __restrict__ bias1)
{
    __shared__ float sw[512];
    __shared__ float red[256];
    __shared__ float sres[64];
    __shared__ float sy[64];
    int bq = blockIdx.x, tid = threadIdx.x;
    int row = src_row(bq);
    const float* Xb = x + (size_t)row * 32768;
    float f0 = fbuf[bq * 512 + tid], f1 = fbuf[bq * 512 + tid + 256];
    float mk0 = masks[bq * 512 + tid], mk1 = masks[bq * 512 + tid + 256];
    float s0 = f0 - (1.f - mk0) * 1e8f, s1 = f1 - (1.f - mk1) * 1e8f;
    red[tid] = fmaxf(s0, s1);
    __syncthreads();
    for (int off = 128; off >= 1; off >>= 1) {
        if (tid < off) red[tid] = fmaxf(red[tid], red[tid + off]);
        __syncthreads();
    }
    float mx = red[0];
    __syncthreads();
    float e0 = expf(s0 - mx), e1 = expf(s1 - mx);
    red[tid] = e0 + e1;
    __syncthreads();
    for (int off = 128; off >= 1; off >>= 1) {
        if (tid < off) red[tid] = red[tid] + red[tid + off];
        __syncthreads();
    }
    float inv = 1.f / red[0];
    __syncthreads();
    sw[tid] = e0 * inv; sw[tid + 256] = e1 * inv;
    __syncthreads();
    int c4 = tid >> 2, p4 = tid & 3;
    {
        float a = 0.f;
        const float* xr = Xb + c4 * 512 + p4 * 128;
        const float* wr = &sw[p4 * 128];
        for (int ii = 0; ii < 128; ++ii) a += xr[ii] * wr[ii];
        red[tid] = a;
    }
    __syncthreads();
    if (p4 == 0) sres[c4] = red[tid] + red[tid + 1] + red[tid + 2] + red[tid + 3];
    __syncthreads();
    if (tid < 64) {
        float a = b_e[tid];
        for (int cc = 0; cc < 64; ++cc) a += w_e[tid * 64 + cc] * sres[cc];
        float sc = g_e[tid] / sqrtf(v_e[tid] + EPS);
        sy[tid] = (a - m_e[tid]) * sc + be_e[tid];
    }
    __syncthreads();
    if (tid < 64) {
        float a = 0.f;
        for (int cc = 0; cc < 64; ++cc) a += w1[tid * 128 + 64 + cc] * sy[cc];
        bias1[bq * 64 + tid] = a;
    }
}

extern "C" void kernel_launch(void* const* d_in, const int* in_sizes, int n_in,
                              void* d_out, int out_size, void* d_ws, size_t ws_size,
                              hipStream_t stream)
{
    const float* x        = (const float*)d_in[0];
    const float* w_reduce = (const float*)d_in[1];
    const float* w_erase  = (const float*)d_in[2];
    const float* b_erase  = (const float*)d_in[3];
    const float* g_erase  = (const float*)d_in[4];
    const float* be_erase = (const float*)d_in[5];
    const float* m_erase  = (const float*)d_in[6];
    const float* v_erase  = (const float*)d_in[7];
    const float* w0 = (const float*)d_in[8];
    const float* g0 = (const float*)d_in[9];
    const float* b0 = (const float*)d_in[10];
    const float* m0 = (const float*)d_in[11];
    const float* v0 = (const float*)d_in[12];
    const float* w1 = (const float*)d_in[13];
    const float* g1 = (const float*)d_in[14];
    const float* b1 = (const float*)d_in[15];
    const float* m1 = (const float*)d_in[16];
    const float* v1 = (const float*)d_in[17];
    float* out = (float*)d_out;
    char* ws = (char*)d_ws;

    _Float16* h0 = (_Float16*)(ws);              // 6.29 MB  split of raw x
    _Float16* l0 = (_Float16*)(ws + 6291456);    // 6.29 MB
    int*   idxA  = (int*)(ws + 12582912);        // 3.15 MB
    int*   idxB  = (int*)(ws + 15728640);        // 3.15 MB
    float* xn0   = (float*)(ws + 18874368);      // 192 KB
    float* bias0 = (float*)(ws + 19070976);      // 24 KB
    float* bias1 = (float*)(ws + 19095552);      // 24 KB
    float* x0vec = (float*)(ws + 19120128);      // 24 KB
    float* fbuf  = (float*)(ws + 19144704);      // 192 KB
    float* masks = (float*)(ws + 19341312);      // 192 KB
    _Float16* wh0 = (_Float16*)(ws + 19537920);  // 16 KB
    _Float16* wl0 = (_Float16*)(ws + 19554304);  // 16 KB
    _Float16* wh1 = (_Float16*)(ws + 19570688);  // 16 KB
    _Float16* wl1 = (_Float16*)(ws + 19587072);  // 16 KB

    (void)in_sizes; (void)n_in; (void)out_size; (void)ws_size;

    prep_kernel<<<768, 256, 0, stream>>>(x, h0, l0, xn0, w0, w1, wh0, wl0, wh1, wl1);
    knn_kernel<0><<<768, 256, 0, stream>>>(h0, l0, xn0, nullptr, 0, idxA, 10);
    erase0_kernel<<<96, 256, 0, stream>>>(x, w0, w_erase, b_erase, g_erase, be_erase, m_erase, v_erase, bias0);
    fused_branch_kernel<0><<<dim3(96, 8), 256, 0, stream>>>(h0, l0, wh0, wl0, idxA, nullptr, 0, bias0,
                                                            g0, b0, m0, v0, out, x0vec);
    corre_kernel<<<96, 256, 0, stream>>>(x, x0vec, w_reduce, idxA, fbuf, masks);
    erase1_kernel<<<96, 256, 0, stream>>>(x, masks, fbuf, w_erase, b_erase, g_erase, be_erase, m_erase, v_erase,
                                          w1, bias1);
    knn_kernel<1><<<768, 256, 0, stream>>>(h0, l0, xn0, masks, 1, idxB, 10);
    fused_branch_kernel<1><<<dim3(96, 8), 256, 0, stream>>>(h0, l0, wh1, wl1, idxB, masks, 1, bias1,
                                                            g1, b1, m1, v1, out, nullptr);
}